// Round 11
// baseline (966.354 us; speedup 1.0000x reference)
//
#include <hip/hip_runtime.h>
#include <math.h>

typedef __bf16 bf16_t;
typedef bf16_t bf16x8 __attribute__((ext_vector_type(8)));
typedef float  f32x4  __attribute__((ext_vector_type(4)));

#define B_  1024
#define T_  64
#define V_  1024
#define E_  512
#define M_  1024
#define L_  32
#define PE_ 512
#define PO_ 511
#define G3_ 1536
#define M2_ 2048

#define MFMA_BF16 __builtin_amdgcn_mfma_f32_16x16x32_bf16

// async global->LDS: dest = wave-uniform base + lane*16
__device__ __forceinline__ void stage16b(bf16_t* lds_base, const bf16_t* gsrc) {
  __builtin_amdgcn_global_load_lds(
      (const __attribute__((address_space(1))) unsigned int*)gsrc,
      (__attribute__((address_space(3))) unsigned int*)lds_base, 16, 0, 0);
}

// fragment-tiled layout: matrix [R][512] stored as 16x32 tiles in MFMA-frag
// order. Element (row,k) at ((row>>4)*16 + (k>>5))*512 + ((k>>3)&3)*128 +
// (row&15)*8 + (k&7)  [elements]. A wave's frag load (16 rows x 32 k) is then
// base + lane*8 elems = contiguous 1KB.
__device__ __forceinline__ size_t tiled_off(int row, int k) {
  return ((size_t)(row >> 4) * 16 + (k >> 5)) * 512 +
         (size_t)(((k >> 3) & 3) * 16 + (row & 15)) * 8 + (k & 7);
}

// ---------------------------------------------------------------- prep (fused)
__device__ __forceinline__ void split_chunk(const float* __restrict__ src,
                                            bf16_t* __restrict__ hi,
                                            bf16_t* __restrict__ lo, int blk,
                                            int tid) {
  int i4 = (blk * 256 + tid) * 4;
  float4 v = *(const float4*)&src[i4];
  float vv[4] = {v.x, v.y, v.z, v.w};
#pragma unroll
  for (int j = 0; j < 4; j++) {
    bf16_t h = (bf16_t)vv[j];
    hi[i4 + j] = h;
    lo[i4 + j] = (bf16_t)(vv[j] - (float)h);
  }
}

// Block ranges:
//  [0,512) embed | [512,1280) W_ih | [1280,2304) Wc | [2304,3328) R_real |
//  [3328,4352) R_imag | [4352,5888) permute W_hh -> Wp in FRAGMENT-TILED
//  layout (rows q=c*96+g*32+e_l) | [5888,5952) Ue | [5952,6016) Uo
// U packing (qc8 16-elem/lane geometry): pair p -> j=p&7, ln=p>>3;
//   A-row float4 at l*4096 + (2j)*256 + ln*4, B-row at +256 -> every qc U
//   read is a contiguous 1KB wave-load.
__global__ __launch_bounds__(256) void prep_all(
    const float* __restrict__ embed, bf16_t* __restrict__ emb_hi,
    bf16_t* __restrict__ emb_lo, const float* __restrict__ W_ih,
    bf16_t* __restrict__ wih_hi, bf16_t* __restrict__ wih_lo,
    const float* __restrict__ Wc, bf16_t* __restrict__ wc_hi,
    bf16_t* __restrict__ wc_lo, const float* __restrict__ R_real,
    bf16_t* __restrict__ rr_hi, bf16_t* __restrict__ rr_lo,
    const float* __restrict__ R_imag, bf16_t* __restrict__ ri_hi,
    bf16_t* __restrict__ ri_lo, const float* __restrict__ W_hh,
    bf16_t* __restrict__ Wp_hi, bf16_t* __restrict__ Wp_lo,
    const float* __restrict__ phase, const float* __restrict__ th_e,
    const float* __restrict__ ph_e, const float* __restrict__ rh_e,
    float* __restrict__ Uep, const float* __restrict__ th_o,
    const float* __restrict__ ph_o, const float* __restrict__ rh_o,
    float* __restrict__ Uop) {
  const int bid = blockIdx.x, tid = threadIdx.x;
  if (bid < 512) {
    split_chunk(embed, emb_hi, emb_lo, bid, tid);
  } else if (bid < 1280) {
    split_chunk(W_ih, wih_hi, wih_lo, bid - 512, tid);
  } else if (bid < 2304) {
    split_chunk(Wc, wc_hi, wc_lo, bid - 1280, tid);
  } else if (bid < 3328) {
    split_chunk(R_real, rr_hi, rr_lo, bid - 2304, tid);
  } else if (bid < 4352) {
    split_chunk(R_imag, ri_hi, ri_lo, bid - 3328, tid);
  } else if (bid < 5888) {
    int q = bid - 4352;  // permuted row: q = c*96 + g*32 + e_l
    int c = q / 96, loc = q % 96;
    int g = loc >> 5, el = loc & 31;
    const float* src = &W_hh[(size_t)(g * 512 + c * 32 + el) * 512];
    if (tid < 64) {
      int k0 = tid * 8;
      float4 v0 = *(const float4*)&src[k0];
      float4 v1 = *(const float4*)&src[k0 + 4];
      float vv[8] = {v0.x, v0.y, v0.z, v0.w, v1.x, v1.y, v1.z, v1.w};
      bf16x8 h8, l8;
#pragma unroll
      for (int j = 0; j < 8; j++) {
        bf16_t h = (bf16_t)vv[j];
        h8[j] = h;
        l8[j] = (bf16_t)(vv[j] - (float)h);
      }
      size_t toff = tiled_off(q, k0);
      *(bf16x8*)&Wp_hi[toff] = h8;
      *(bf16x8*)&Wp_lo[toff] = l8;
    }
  } else if (bid < 5952) {
    int idx = (bid - 5888) * 256 + tid;
    if (idx < L_ * PE_) {
      int l = idx >> 9, p = idx & 511;
      float t = th_e[idx], pp = ph_e[idx], r = rh_e[idx];
      float c = cosf(t), s = sinf(t);
      float cp = cosf(pp), sp = sinf(pp), cr = cosf(r), sr = sinf(r);
      float u11r = c * (cp * cr - sp * sr), u11i = c * (cp * sr + sp * cr);
      float u12r = -s * sp, u12i = s * cp;
      float u21r = -s * sr, u21i = s * cr;
      float u22r = c, u22i = 0.0f;
      float f0 = phase[l * M_ + 2 * p], f1 = phase[l * M_ + 2 * p + 1];
      float c0 = cosf(f0), s0 = sinf(f0), c1 = cosf(f1), s1 = sinf(f1);
      float a, b;
      a = u11r * c0 - u11i * s0; b = u11r * s0 + u11i * c0; u11r = a; u11i = b;
      a = u21r * c0 - u21i * s0; b = u21r * s0 + u21i * c0; u21r = a; u21i = b;
      a = u12r * c1 - u12i * s1; b = u12r * s1 + u12i * c1; u12r = a; u12i = b;
      a = u22r * c1 - u22i * s1; b = u22r * s1 + u22i * c1; u22r = a; u22i = b;
      int j = p & 7, ln = p >> 3;
      size_t base = (size_t)l * 4096 + (size_t)(2 * j) * 256 + ln * 4;
      *(float4*)&Uep[base]       = make_float4(u11r, u11i, u12r, u12i);
      *(float4*)&Uep[base + 256] = make_float4(u21r, u21i, u22r, u22i);
    }
  } else {
    int idx = (bid - 5952) * 256 + tid;
    if (idx < L_ * PO_) {
      int l = idx / PO_, p = idx % PO_;
      float t = th_o[idx], pp = ph_o[idx], r = rh_o[idx];
      float c = cosf(t), s = sinf(t);
      float cp = cosf(pp), sp = sinf(pp), cr = cosf(r), sr = sinf(r);
      int j = p & 7, ln = p >> 3;
      size_t base = (size_t)l * 4096 + (size_t)(2 * j) * 256 + ln * 4;
      *(float4*)&Uop[base] = make_float4(c * (cp * cr - sp * sr),
                                         c * (cp * sr + sp * cr), -s * sp,
                                         s * cp);
      *(float4*)&Uop[base + 256] = make_float4(-s * sr, s * cr, c, 0.0f);
    }
  }
}

// ---------------------------------------------------------------- generic split GEMM
__global__ __launch_bounds__(256) void gemm_bt_mfma_split(
    const bf16_t* __restrict__ Ah, const bf16_t* __restrict__ Al,
    const bf16_t* __restrict__ Bh, const bf16_t* __restrict__ Bl,
    float* __restrict__ C, int Ndim, int K) {
  __shared__ bf16_t sAh[64 * 32], sAl[64 * 32], sBh[64 * 32], sBl[64 * 32];
  const int tid = threadIdx.x;
  const int m0 = blockIdx.y * 64, n0 = blockIdx.x * 64;
  const int wave = tid >> 6, lane = tid & 63;
  const int wr = wave >> 1, wc = wave & 1;
  const int quad = lane >> 4, l16 = lane & 15;
  f32x4 acc[2][2] = {};
  const int srow = tid >> 2, sk = (tid & 3) * 8;

  for (int k0 = 0; k0 < K; k0 += 32) {
    bf16x8 ah = *(const bf16x8*)&Ah[(size_t)(m0 + srow) * K + k0 + sk];
    bf16x8 al = *(const bf16x8*)&Al[(size_t)(m0 + srow) * K + k0 + sk];
    bf16x8 bh = *(const bf16x8*)&Bh[(size_t)(n0 + srow) * K + k0 + sk];
    bf16x8 bl = *(const bf16x8*)&Bl[(size_t)(n0 + srow) * K + k0 + sk];
    __syncthreads();
    *(bf16x8*)&sAh[srow * 32 + sk] = ah;
    *(bf16x8*)&sAl[srow * 32 + sk] = al;
    *(bf16x8*)&sBh[srow * 32 + sk] = bh;
    *(bf16x8*)&sBl[srow * 32 + sk] = bl;
    __syncthreads();
    bf16x8 fAh[2], fAl[2], fBh[2], fBl[2];
#pragma unroll
    for (int i = 0; i < 2; i++) {
      fAh[i] = *(const bf16x8*)&sAh[(wr * 32 + i * 16 + l16) * 32 + quad * 8];
      fAl[i] = *(const bf16x8*)&sAl[(wr * 32 + i * 16 + l16) * 32 + quad * 8];
      fBh[i] = *(const bf16x8*)&sBh[(wc * 32 + i * 16 + l16) * 32 + quad * 8];
      fBl[i] = *(const bf16x8*)&sBl[(wc * 32 + i * 16 + l16) * 32 + quad * 8];
    }
#pragma unroll
    for (int i = 0; i < 2; i++)
#pragma unroll
      for (int j = 0; j < 2; j++) {
        acc[i][j] = MFMA_BF16(fAh[i], fBh[j], acc[i][j], 0, 0, 0);
        acc[i][j] = MFMA_BF16(fAh[i], fBl[j], acc[i][j], 0, 0, 0);
        acc[i][j] = MFMA_BF16(fAl[i], fBh[j], acc[i][j], 0, 0, 0);
      }
  }
#pragma unroll
  for (int i = 0; i < 2; i++)
#pragma unroll
    for (int j = 0; j < 2; j++)
#pragma unroll
      for (int r = 0; r < 4; r++) {
        int row = wr * 32 + i * 16 + quad * 4 + r;
        int col = wc * 32 + j * 16 + l16;
        C[(size_t)(m0 + row) * Ndim + n0 + col] = acc[i][j][r];
      }
}

// ---------------------------------------------------------------- GRU step (v11: A direct, B via gload_lds dbuf)
// r8 lesson: per barrier interval, DMA bytes must be covered by that
// interval's MFMA work. This r7 structure (A direct vmcnt-pipelined, B DMA
// at BK=64 with 2 MFMA sub-steps of cover) is the measured family optimum.
__global__ __launch_bounds__(512) void gru_step11(
    const bf16_t* __restrict__ Hh, const bf16_t* __restrict__ Hl,
    const bf16_t* __restrict__ Wph, const bf16_t* __restrict__ Wpl,
    const int* __restrict__ tok, const float* __restrict__ eg,
    const float* __restrict__ b_ih, const float* __restrict__ b_hh,
    bf16_t* __restrict__ Oh, bf16_t* __restrict__ Ol, int t, int final_) {
  __shared__ bf16_t sB[2][2][24 * 512];   // [dbuf][group][hi:0-11|lo:12-23] 96KB
  __shared__ float sC[2][64 * 100];
  __shared__ float sbih[96], sbhh[96];
  const int tid = threadIdx.x;
  const int g = tid >> 8;                       // k-group (k in [g*256,(g+1)*256))
  const int gtid = tid & 255;
  const int ct = blockIdx.y, m0 = blockIdx.x * 64;  // bt fast, ct slow
  const int n0e = ct * 32;
  const int wg = gtid >> 6, lane = tid & 63;
  const int wr = wg >> 1, wc = wg & 1;
  const int quad = lane >> 4, l16 = lane & 15;

  // staging: 24 chunks/group/iter (12 hi + 12 lo), 6 per wave.
#define STAGE_B(buf, it)                                                      \
  {                                                                           \
    _Pragma("unroll") for (int r = 0; r < 6; r++) {                           \
      int c = wg * 6 + r;                                                     \
      int f = (c >= 12) ? (c - 12) : c;                                       \
      int j = f >> 1, ks = f & 1;                                             \
      const bf16_t* srcp = (c < 12) ? Wph : Wpl;                              \
      stage16b(&sB[buf][g][c * 512],                                          \
               &srcp[(size_t)(ct * 6 + j) * 8192 +                            \
                     (size_t)(g * 8 + (it) * 2 + ks) * 512 + lane * 8]);      \
    }                                                                         \
  }

  STAGE_B(0, 0);

  if (tid < 96) {
    sbih[tid] = b_ih[(tid >> 5) * 512 + n0e + (tid & 31)];
    sbhh[tid] = b_hh[(tid >> 5) * 512 + n0e + (tid & 31)];
  }

  float pir[4], piz[4], pin[4], phv[4];
#pragma unroll
  for (int u = 0; u < 4; u++) {
    int flat = u * 512 + tid;           // 0..2047 = 64 rows x 32 els
    int row = flat >> 5, el = flat & 31;
    int bb = m0 + row, eG = n0e + el;
    int tk = tok[bb * T_ + t];
    pir[u] = eg[(size_t)tk * G3_ + eG];
    piz[u] = eg[(size_t)tk * G3_ + 512 + eG];
    pin[u] = eg[(size_t)tk * G3_ + 1024 + eG];
    size_t toff = tiled_off(bb, eG);
    phv[u] = (float)Hh[toff] + (float)Hl[toff];
  }

  // A fragment bases (elements): frag (rt, kb) at rt*8192 + kb*512 + lane*8
  const size_t aB0 = (size_t)((m0 >> 4) + wr * 2 + 0) * 8192 + (size_t)g * 4096 + lane * 8;
  const size_t aB1 = (size_t)((m0 >> 4) + wr * 2 + 1) * 8192 + (size_t)g * 4096 + lane * 8;

  f32x4 acc[2][3] = {};
  __syncthreads();  // drain STAGE_B(0,0)
#pragma unroll
  for (int it = 0; it < 4; ++it) {
    const int buf = it & 1;
    if (it < 3) STAGE_B(buf ^ 1, it + 1);
    const bf16_t* sBg = &sB[buf][g][0];
#pragma unroll
    for (int ks2 = 0; ks2 < 2; ++ks2) {
      const int kb = it * 2 + ks2;      // within-group kb 0..7 ascending
      const int ko = kb * 512;
      bf16x8 fah[2], fal[2], fbh[3], fbl[3];
      fah[0] = *(const bf16x8*)&Hh[aB0 + ko];
      fah[1] = *(const bf16x8*)&Hh[aB1 + ko];
      fal[0] = *(const bf16x8*)&Hl[aB0 + ko];
      fal[1] = *(const bf16x8*)&Hl[aB1 + ko];
#pragma unroll
      for (int j = 0; j < 3; j++) {
        int f = (wc * 3 + j) * 2 + ks2;
        fbh[j] = *(const bf16x8*)&sBg[f * 512 + lane * 8];
        fbl[j] = *(const bf16x8*)&sBg[(f + 12) * 512 + lane * 8];
      }
#pragma unroll
      for (int i = 0; i < 2; i++)
#pragma unroll
        for (int j = 0; j < 3; j++) {
          acc[i][j] = MFMA_BF16(fah[i], fbh[j], acc[i][j], 0, 0, 0);
          acc[i][j] = MFMA_BF16(fah[i], fbl[j], acc[i][j], 0, 0, 0);
          acc[i][j] = MFMA_BF16(fal[i], fbh[j], acc[i][j], 0, 0, 0);
        }
    }
    __syncthreads();  // drains next-iter DMA; protects buf reuse
  }
#undef STAGE_B
#pragma unroll
  for (int i = 0; i < 2; i++)
#pragma unroll
    for (int j = 0; j < 3; j++)
#pragma unroll
      for (int r = 0; r < 4; r++)
        sC[g][(wr * 32 + i * 16 + quad * 4 + r) * 100 + wc * 48 + j * 16 + l16] =
            acc[i][j][r];
  __syncthreads();
#pragma unroll
  for (int u = 0; u < 4; u++) {
    int flat = u * 512 + tid;
    int row = flat >> 5, el = flat & 31;
    int bb = m0 + row, eG = n0e + el;
    float ir = pir[u] + sbih[el];
    float iz = piz[u] + sbih[32 + el];
    float in_ = pin[u] + sbih[64 + el];
    float hr = sC[0][row * 100 + el] + sC[1][row * 100 + el] + sbhh[el];
    float hz = sC[0][row * 100 + 32 + el] + sC[1][row * 100 + 32 + el] + sbhh[32 + el];
    float hn = sC[0][row * 100 + 64 + el] + sC[1][row * 100 + 64 + el] + sbhh[64 + el];
    float r = 1.0f / (1.0f + __expf(-(ir + hr)));
    float z = 1.0f / (1.0f + __expf(-(iz + hz)));
    float targ = fminf(fmaxf(in_ + r * hn, -15.0f), 15.0f);
    float e2 = __expf(2.0f * targ);
    float n = (e2 - 1.0f) / (e2 + 1.0f);
    float hnew = (1.0f - z) * n + z * phv[u];
    bf16_t hh = (bf16_t)hnew;
    bf16_t ll = (bf16_t)(hnew - (float)hh);
    if (final_) {
      size_t hidx = (size_t)bb * 512 + eG;  // row-major for zc GEMM
      Oh[hidx] = hh;
      Ol[hidx] = ll;
    } else {
      size_t toff = tiled_off(bb, eG);
      Oh[toff] = hh;
      Ol[toff] = ll;
    }
  }
}

// ---------------------------------------------------------------- MZI core (qc8: 2 b's per wave, zero-LDS, zero-barrier)
// r10 ledger: qc7 is L1-port-bound on U reads (4 waves/CU x 16KB/layer =
// 128KB/layer/CU ~ 27us floor). qc8 halves it: one wave owns TWO b's in
// qc4's 16-complex/lane layout (all exchange via shfl, no LDS, no barriers),
// so one set of U loads serves both b's -> 64KB/layer/CU. The two b-chains
// are independent -> in-wave ILP hides FMA latency (qc4's weakness), and
// with zero barriers the compiler pipelines next-layer loads under compute.
// Per-b FMA order identical to the verified qc4 structure.
__device__ inline void apply_u(float4 A, float4 Bv, float& x0r, float& x0i,
                               float& x1r, float& x1i) {
  float n0r = A.x * x0r - A.y * x0i + A.z * x1r - A.w * x1i;
  float n0i = A.x * x0i + A.y * x0r + A.z * x1i + A.w * x1r;
  float n1r = Bv.x * x0r - Bv.y * x0i + Bv.z * x1r - Bv.w * x1i;
  float n1i = Bv.x * x0i + Bv.y * x0r + Bv.z * x1i + Bv.w * x1r;
  x0r = n0r; x0i = n0i; x1r = n1r; x1i = n1i;
}

__global__ __launch_bounds__(64) void qc8(
    const float* __restrict__ zc, const float* __restrict__ bc,
    const float* __restrict__ Uep, const float* __restrict__ Uop,
    bf16_t* __restrict__ prh, bf16_t* __restrict__ prl,
    bf16_t* __restrict__ pih, bf16_t* __restrict__ pil) {
  const int lane = threadIdx.x;
  const int b0 = blockIdx.x * 2, b1 = b0 + 1;
  const int e0 = lane * 16;

  float xr0[16], xi0[16], xr1[16], xi1[16];
#define LOAD_B(bb, xr, xi)                                                    \
  {                                                                           \
    const float4* zr4 = (const float4*)&zc[(size_t)(bb) * M2_ + e0];          \
    const float4* zi4 = (const float4*)&zc[(size_t)(bb) * M2_ + M_ + e0];     \
    const float4* br4 = (const float4*)&bc[e0];                               \
    const float4* bi4 = (const float4*)&bc[M_ + e0];                          \
    _Pragma("unroll") for (int q = 0; q < 4; q++) {                           \
      float4 a = zr4[q], b4 = br4[q];                                         \
      xr[4 * q + 0] = a.x + b4.x; xr[4 * q + 1] = a.y + b4.y;                 \
      xr[4 * q + 2] = a.z + b4.z; xr[4 * q + 3] = a.w + b4.w;                 \
      float4 c4 = zi4[q], d4 = bi4[q];                                        \
      xi[4 * q + 0] = c4.x + d4.x; xi[4 * q + 1] = c4.y + d4.y;               \
      xi[4 * q + 2] = c4.z + d4.z; xi[4 * q + 3] = c4.w + d4.w;               \
    }                                                                         \
  }
  LOAD_B(b0, xr0, xi0);
  LOAD_B(b1, xr1, xi1);
#undef LOAD_B

#define NORM_B(xr, xi)                                                        \
  {                                                                           \
    float s = 0.0f;                                                           \
    _Pragma("unroll") for (int k = 0; k < 16; k++)                            \
        s += xr[k] * xr[k] + xi[k] * xi[k];                                   \
    for (int off = 32; off; off >>= 1) s += __shfl_xor(s, off);               \
    float inv = 1.0f / sqrtf(s + 1e-8f);                                      \
    _Pragma("unroll") for (int k = 0; k < 16; k++) {                          \
      xr[k] *= inv; xi[k] *= inv;                                             \
    }                                                                         \
  }
  NORM_B(xr0, xi0);
  NORM_B(xr1, xi1);
#undef NORM_B

#pragma unroll 1
  for (int l = 0; l < L_; ++l) {
    const float* Ub = &Uep[(size_t)l * 4096];
    const float* Ob = &Uop[(size_t)l * 4096];
    // even: pairs p = 8*lane + j, elems (2j, 2j+1); one load serves both b's
    {
      float4 eA[8], eB[8];
#pragma unroll
      for (int j = 0; j < 8; j++) {
        eA[j] = *(const float4*)&Ub[(2 * j) * 256 + lane * 4];
        eB[j] = *(const float4*)&Ub[(2 * j + 1) * 256 + lane * 4];
      }
#pragma unroll
      for (int j = 0; j < 8; j++) {
        apply_u(eA[j], eB[j], xr0[2 * j], xi0[2 * j], xr0[2 * j + 1],
                xi0[2 * j + 1]);
        apply_u(eA[j], eB[j], xr1[2 * j], xi1[2 * j], xr1[2 * j + 1],
                xi1[2 * j + 1]);
      }
    }
    // odd: pairs q = 8*lane + j, elems (2j+1, 2j+2); j=7 crosses to lane+1
    {
      float4 oA[8], oB[8];
#pragma unroll
      for (int j = 0; j < 8; j++) {
        oA[j] = *(const float4*)&Ob[(2 * j) * 256 + lane * 4];
        oB[j] = *(const float4*)&Ob[(2 * j + 1) * 256 + lane * 4];
      }
      // post-even x[0] of lane+1 (input to the boundary pair)
      float nr0 = __shfl_down(xr0[0], 1), ni0 = __shfl_down(xi0[0], 1);
      float nr1 = __shfl_down(xr1[0], 1), ni1 = __shfl_down(xi1[0], 1);
#pragma unroll
      for (int j = 0; j < 7; j++) {
        apply_u(oA[j], oB[j], xr0[2 * j + 1], xi0[2 * j + 1], xr0[2 * j + 2],
                xi0[2 * j + 2]);
        apply_u(oA[j], oB[j], xr1[2 * j + 1], xi1[2 * j + 1], xr1[2 * j + 2],
                xi1[2 * j + 2]);
      }
      float s0r = 0.f, s0i = 0.f, s1r = 0.f, s1i = 0.f;
      if (lane < 63) {  // boundary pair q=8*lane+7 (q=511 doesn't exist)
        {
          float4 A = oA[7], Bv = oB[7];
          float n0r = A.x * xr0[15] - A.y * xi0[15] + A.z * nr0 - A.w * ni0;
          float n0i = A.x * xi0[15] + A.y * xr0[15] + A.z * ni0 + A.w * nr0;
          s0r = Bv.x * xr0[15] - Bv.y * xi0[15] + Bv.z * nr0 - Bv.w * ni0;
          s0i = Bv.x * xi0[15] + Bv.y * xr0[15] + Bv.z * ni0 + Bv.w * nr0;
          xr0[15] = n0r; xi0[15] = n0i;
        }
        {
          float4 A = oA[7], Bv = oB[7];
          float n0r = A.x * xr1[15] - A.y * xi1[15] + A.z * nr1 - A.w * ni1;
          float n0i = A.x * xi1[15] + A.y * xr1[15] + A.z * ni1 + A.w * nr1;
          s1r = Bv.x * xr1[15] - Bv.y * xi1[15] + Bv.z * nr1 - Bv.w * ni1;
          s1i = Bv.x * xi1[15] + Bv.y * xr1[15] + Bv.z * ni1 + Bv.w * nr1;
          xr1[15] = n0r; xi1[15] = n0i;
        }
      }
      float r0 = __shfl_up(s0r, 1), i0 = __shfl_up(s0i, 1);
      float r1 = __shfl_up(s1r, 1), i1 = __shfl_up(s1i, 1);
      if (lane > 0) {
        xr0[0] = r0; xi0[0] = i0;
        xr1[0] = r1; xi1[0] = i1;
      }
    }
  }

#define STORE_B(bb, xr, xi)                                                   \
  {                                                                           \
    size_t base = (size_t)(bb) * M_ + e0;                                     \
    _Pragma("unroll") for (int half = 0; half < 2; half++) {                  \
      bf16x8 vh, vl, wh, wl;                                                  \
      _Pragma("unroll") for (int k = 0; k < 8; k++) {                         \
        float vr = xr[half * 8 + k], vi = xi[half * 8 + k];                   \
        bf16_t h1 = (bf16_t)vr;                                               \
        vh[k] = h1; vl[k] = (bf16_t)(vr - (float)h1);                         \
        bf16_t h2 = (bf16_t)vi;                                               \
        wh[k] = h2; wl[k] = (bf16_t)(vi - (float)h2);                         \
      }                                                                       \
      *(bf16x8*)&prh[base + half * 8] = vh;                                   \
      *(bf16x8*)&prl[base + half * 8] = vl;                                   \
      *(bf16x8*)&pih[base + half * 8] = wh;                                   \
      *(bf16x8*)&pil[base + half * 8] = wl;                                   \
    }                                                                         \
  }
  STORE_B(b0, xr0, xi0);
  STORE_B(b1, xr1, xi1);
#undef STORE_B
}

// ---------------------------------------------------------------- readout (r7 known-good)
// r9 lesson: K-split pays only when MFMA-per-interval is thin; readout has
// 48 MFMA/interval (compute-covered at 1 wave/SIMD).
__global__ __launch_bounds__(256) void readout_mfma(
    const bf16_t* __restrict__ Arh, const bf16_t* __restrict__ Arl,
    const bf16_t* __restrict__ Aih, const bf16_t* __restrict__ Ail,
    const bf16_t* __restrict__ Brh, const bf16_t* __restrict__ Brl,
    const bf16_t* __restrict__ Bih, const bf16_t* __restrict__ Bil,
    float* __restrict__ out) {
  __shared__ bf16_t sArh[64 * 32], sArl[64 * 32], sAih[64 * 32], sAil[64 * 32];
  __shared__ bf16_t sBrh[64 * 32], sBrl[64 * 32], sBih[64 * 32], sBil[64 * 32];
  const int tid = threadIdx.x;
  const int b0 = blockIdx.y * 64, v0 = blockIdx.x * 64;
  const int wave = tid >> 6, lane = tid & 63;
  const int wr = wave >> 1, wc = wave & 1;
  const int quad = lane >> 4, l16 = lane & 15;
  f32x4 aP[2][2] = {}, aQ[2][2] = {}, aI[2][2] = {};
  const int srow = tid >> 2, sk = (tid & 3) * 8;

  for (int k0 = 0; k0 < M_; k0 += 32) {
    size_t aoff = (size_t)(b0 + srow) * M_ + k0 + sk;
    size_t boff = (size_t)(v0 + srow) * M_ + k0 + sk;
    bf16x8 v0r = *(const bf16x8*)&Arh[aoff];
    bf16x8 v1r = *(const bf16x8*)&Arl[aoff];
    bf16x8 v2r = *(const bf16x8*)&Aih[aoff];
    bf16x8 v3r = *(const bf16x8*)&Ail[aoff];
    bf16x8 v4r = *(const bf16x8*)&Brh[boff];
    bf16x8 v5r = *(const bf16x8*)&Brl[boff];
    bf16x8 v6r = *(const bf16x8*)&Bih[boff];
    bf16x8 v7r = *(const bf16x8*)&Bil[boff];
    __syncthreads();
    *(bf16x8*)&sArh[srow * 32 + sk] = v0r;
    *(bf16x8*)&sArl[srow * 32 + sk] = v1r;
    *(bf16x8*)&sAih[srow * 32 + sk] = v2r;
    *(bf16x8*)&sAil[srow * 32 + sk] = v3r;
    *(bf16x8*)&sBrh[srow * 32 + sk] = v4r;
    *(bf16x8*)&sBrl[srow * 32 + sk] = v5r;
    *(bf16x8*)&sBih[srow * 32 + sk] = v6r;
    *(bf16x8*)&sBil[srow * 32 + sk] = v7r;
    __syncthreads();
    bf16x8 fArh[2], fArl[2], fAih[2], fAil[2], fBrh[2], fBrl[2], fBih[2], fBil[2];
#pragma unroll
    for (int i = 0; i < 2; i++) {
      int ra = (wr * 32 + i * 16 + l16) * 32 + quad * 8;
      int rb = (wc * 32 + i * 16 + l16) * 32 + quad * 8;
      fArh[i] = *(const bf16x8*)&sArh[ra];
      fArl[i] = *(const bf16x8*)&sArl[ra];
      fAih[i] = *(const bf16x8*)&sAih[ra];
      fAil[i] = *(const bf16x8*)&sAil[ra];
      fBrh[i] = *(const bf16x8*)&sBrh[rb];
      fBrl[i] = *(const bf16x8*)&sBrl[rb];
      fBih[i] = *(const bf16x8*)&sBih[rb];
      fBil[i] = *(const bf16x8*)&sBil[rb];
    }
#pragma unroll
    for (int i = 0; i < 2; i++)
#pragma unroll
      for (int j = 0; j < 2; j++) {
        aP[i][j] = MFMA_BF16(fArh[i], fBrh[j], aP[i][j], 0, 0, 0);
        aP[i][j] = MFMA_BF16(fArh[i], fBrl[j], aP[i][j], 0, 0, 0);
        aP[i][j] = MFMA_BF16(fArl[i], fBrh[j], aP[i][j], 0, 0, 0);
        aQ[i][j] = MFMA_BF16(fAih[i], fBih[j], aQ[i][j], 0, 0, 0);
        aQ[i][j] = MFMA_BF16(fAih[i], fBil[j], aQ[i][j], 0, 0, 0);
        aQ[i][j] = MFMA_BF16(fAil[i], fBih[j], aQ[i][j], 0, 0, 0);
        aI[i][j] = MFMA_BF16(fArh[i], fBih[j], aI[i][j], 0, 0, 0);
        aI[i][j] = MFMA_BF16(fArh[i], fBil[j], aI[i][j], 0, 0, 0);
        aI[i][j] = MFMA_BF16(fArl[i], fBih[j], aI[i][j], 0, 0, 0);
        aI[i][j] = MFMA_BF16(fAih[i], fBrh[j], aI[i][j], 0, 0, 0);
        aI[i][j] = MFMA_BF16(fAih[i], fBrl[j], aI[i][j], 0, 0, 0);
        aI[i][j] = MFMA_BF16(fAil[i], fBrh[j], aI[i][j], 0, 0, 0);
      }
  }
#pragma unroll
  for (int i = 0; i < 2; i++)
#pragma unroll
    for (int j = 0; j < 2; j++)
#pragma unroll
      for (int r = 0; r < 4; r++) {
        int row = wr * 32 + i * 16 + quad * 4 + r;
        int col = wc * 32 + j * 16 + l16;
        float re = aP[i][j][r] - aQ[i][j][r];
        float im = aI[i][j][r];
        out[(size_t)(b0 + row) * V_ + v0 + col] = logf(re * re + im * im + 1e-12f);
      }
}

// ---------------------------------------------------------------- logsumexp
__global__ __launch_bounds__(256) void lse_kernel(float* __restrict__ out) {
  __shared__ float redm[4], reds[4];
  const int b = blockIdx.x, t = threadIdx.x;
  float4 v = *(float4*)&out[(size_t)b * V_ + 4 * t];
  float mx = fmaxf(fmaxf(v.x, v.y), fmaxf(v.z, v.w));
  for (int off = 32; off; off >>= 1) mx = fmaxf(mx, __shfl_down(mx, off, 64));
  if ((t & 63) == 0) redm[t >> 6] = mx;
  __syncthreads();
  mx = fmaxf(fmaxf(redm[0], redm[1]), fmaxf(redm[2], redm[3]));
  float s = expf(v.x - mx) + expf(v.y - mx) + expf(v.z - mx) + expf(v.w - mx);
  for (int off = 32; off; off >>= 1) s += __shfl_down(s, off, 64);
  if ((t & 63) == 0) reds[t >> 6] = s;
  __syncthreads();
  s = reds[0] + reds[1] + reds[2] + reds[3];
  float lse = mx + logf(s);
  v.x -= lse; v.y -= lse; v.z -= lse; v.w -= lse;
  *(float4*)&out[(size_t)b * V_ + 4 * t] = v;
}

// ---------------------------------------------------------------- launch
extern "C" void kernel_launch(void* const* d_in, const int* in_sizes, int n_in,
                              void* d_out, int out_size, void* d_ws, size_t ws_size,
                              hipStream_t stream) {
  const int*   tokens = (const int*)d_in[0];
  const float* embed  = (const float*)d_in[1];
  const float* W_ih   = (const float*)d_in[2];
  const float* W_hh   = (const float*)d_in[3];
  const float* b_ih   = (const float*)d_in[4];
  const float* b_hh   = (const float*)d_in[5];
  const float* Wc     = (const float*)d_in[6];
  const float* bc     = (const float*)d_in[7];
  const float* phase  = (const float*)d_in[8];
  const float* theta_e = (const float*)d_in[9];
  const float* phi_e  = (const float*)d_in[10];
  const float* rho_e  = (const float*)d_in[11];
  const float* theta_o = (const float*)d_in[12];
  const float* phi_o  = (const float*)d_in[13];
  const float* rho_o  = (const float*)d_in[14];
  const float* R_real = (const float*)d_in[15];
  const float* R_imag = (const float*)d_in[16];
  float* out = (float*)d_out;

  char* w = (char*)d_ws;
  auto alloc = [&](size_t bytes) -> void* {
    void* p = (void*)w;
    w += (bytes + 255) & ~(size_t)255;
    return p;
  };
  // region0: weight splits; later aliased by psi hi/lo (dead by then)
  char* region0 = w;
  bf16_t* emb_hi = (bf16_t*)alloc((size_t)V_ * E_ * 2);
  bf16_t* emb_lo = (bf16_t*)alloc((size_t)V_ * E_ * 2);
  bf16_t* wih_hi = (bf16_t*)alloc((size_t)G3_ * E_ * 2);
  bf16_t* wih_lo = (bf16_t*)alloc((size_t)G3_ * E_ * 2);
  bf16_t* wc_hi  = (bf16_t*)alloc((size_t)M2_ * E_ * 2);
  bf16_t* wc_lo  = (bf16_t*)alloc((size_t)M2_ * E_ * 2);
  // region1: eg + Wp; later aliased by zc
  char* region1 = w;
  float*  eg     = (float*)alloc((size_t)V_ * G3_ * 4);
  bf16_t* Wp_hi  = (bf16_t*)alloc((size_t)G3_ * E_ * 2);
  bf16_t* Wp_lo  = (bf16_t*)alloc((size_t)G3_ * E_ * 2);
  // persistent
  bf16_t* h0_hi = (bf16_t*)alloc((size_t)B_ * E_ * 2);
  bf16_t* h0_lo = (bf16_t*)alloc((size_t)B_ * E_ * 2);
  bf16_t* h1_hi = (bf16_t*)alloc((size_t)B_ * E_ * 2);
  bf16_t* h1_lo = (bf16_t*)alloc((size_t)B_ * E_ * 2);
  bf16_t* rr_hi = (bf16_t*)alloc((size_t)V_ * M_ * 2);
  bf16_t* rr_lo = (bf16_t*)alloc((size_t)V_ * M_ * 2);
  bf16_t* ri_hi = (bf16_t*)alloc((size_t)V_ * M_ * 2);
  bf16_t* ri_lo = (bf16_t*)alloc((size_t)V_ * M_ * 2);
  float*  Uep   = (float*)alloc((size_t)L_ * 4096 * 4);
  float*  Uop   = (float*)alloc((size_t)L_ * 4096 * 4);

  // aliases
  float*  zc  = (float*)region1;
  bf16_t* prh = (bf16_t*)(region0 + 0 * 2097152);
  bf16_t* prl = (bf16_t*)(region0 + 1 * 2097152);
  bf16_t* pih = (bf16_t*)(region0 + 2 * 2097152);
  bf16_t* pil = (bf16_t*)(region0 + 3 * 2097152);

  hipMemsetAsync(h0_hi, 0, (size_t)B_ * E_ * 2 * 2, stream);

  // ONE fused prep launch
  prep_all<<<6016, 256, 0, stream>>>(
      embed, emb_hi, emb_lo, W_ih, wih_hi, wih_lo, Wc, wc_hi, wc_lo, R_real,
      rr_hi, rr_lo, R_imag, ri_hi, ri_lo, W_hh, Wp_hi, Wp_lo, phase, theta_e,
      phi_e, rho_e, Uep, theta_o, phi_o, rho_o, Uop);

  // eg = embed @ W_ih^T  (V x 3E)
  {
    dim3 grid(G3_ / 64, V_ / 64);
    gemm_bt_mfma_split<<<grid, 256, 0, stream>>>(emb_hi, emb_lo, wih_hi, wih_lo,
                                                 eg, G3_, E_);
  }

  // GRU: 64 per-step launches; A direct tiled, B via gload_lds dbuf (r7 opt)
  for (int t = 0; t < T_; ++t) {
    const bf16_t* ih = (t & 1) ? h1_hi : h0_hi;
    const bf16_t* il = (t & 1) ? h1_lo : h0_lo;
    bf16_t* oh = (t & 1) ? h0_hi : h1_hi;
    bf16_t* ol = (t & 1) ? h0_lo : h1_lo;
    dim3 grid(16, 16);  // bt fast, ct slow (L2 locality)
    gru_step11<<<grid, 512, 0, stream>>>(ih, il, Wp_hi, Wp_lo, tokens, eg,
                                         b_ih, b_hh, oh, ol, t,
                                         (t == T_ - 1) ? 1 : 0);
  }

  // zc = h @ Wc^T  (B x 2M); final h (row-major) in buffer 0 after t=63
  {
    dim3 grid(M2_ / 64, B_ / 64);
    gemm_bt_mfma_split<<<grid, 256, 0, stream>>>(h0_hi, h0_lo, wc_hi, wc_lo,
                                                 zc, M2_, E_);
  }

  // MZI stack (qc8: 2 b's per wave, zero-LDS, zero-barrier)
  qc8<<<B_ / 2, 64, 0, stream>>>(zc, bc, Uep, Uop, prh, prl, pih, pil);

  // readout (r7 known-good)
  {
    dim3 grid(V_ / 64, B_ / 64);
    readout_mfma<<<grid, 256, 0, stream>>>(prh, prl, pih, pil, rr_hi, rr_lo,
                                           ri_hi, ri_lo, out);
  }

  // logsumexp
  lse_kernel<<<B_, 256, 0, stream>>>(out);
}

// Round 12
// 843.149 us; speedup vs baseline: 1.1461x; 1.1461x over previous
//
#include <hip/hip_runtime.h>
#include <math.h>

typedef __bf16 bf16_t;
typedef bf16_t bf16x8 __attribute__((ext_vector_type(8)));
typedef float  f32x4  __attribute__((ext_vector_type(4)));

#define B_  1024
#define T_  64
#define V_  1024
#define E_  512
#define M_  1024
#define L_  32
#define PE_ 512
#define PO_ 511
#define G3_ 1536
#define M2_ 2048

#define MFMA_BF16 __builtin_amdgcn_mfma_f32_16x16x32_bf16

// async global->LDS: dest = wave-uniform base + lane*16
__device__ __forceinline__ void stage16b(bf16_t* lds_base, const bf16_t* gsrc) {
  __builtin_amdgcn_global_load_lds(
      (const __attribute__((address_space(1))) unsigned int*)gsrc,
      (__attribute__((address_space(3))) unsigned int*)lds_base, 16, 0, 0);
}

// fragment-tiled layout: matrix [R][512] stored as 16x32 tiles in MFMA-frag
// order. Element (row,k) at ((row>>4)*16 + (k>>5))*512 + ((k>>3)&3)*128 +
// (row&15)*8 + (k&7)  [elements]. A wave's frag load (16 rows x 32 k) is then
// base + lane*8 elems = contiguous 1KB.
__device__ __forceinline__ size_t tiled_off(int row, int k) {
  return ((size_t)(row >> 4) * 16 + (k >> 5)) * 512 +
         (size_t)(((k >> 3) & 3) * 16 + (row & 15)) * 8 + (k & 7);
}

// ---------------------------------------------------------------- prep (fused)
__device__ __forceinline__ void split_chunk(const float* __restrict__ src,
                                            bf16_t* __restrict__ hi,
                                            bf16_t* __restrict__ lo, int blk,
                                            int tid) {
  int i4 = (blk * 256 + tid) * 4;
  float4 v = *(const float4*)&src[i4];
  float vv[4] = {v.x, v.y, v.z, v.w};
#pragma unroll
  for (int j = 0; j < 4; j++) {
    bf16_t h = (bf16_t)vv[j];
    hi[i4 + j] = h;
    lo[i4 + j] = (bf16_t)(vv[j] - (float)h);
  }
}

// Block ranges:
//  [0,512) embed | [512,1280) W_ih | [1280,2304) Wc | [2304,3328) R_real |
//  [3328,4352) R_imag | [4352,5888) permute W_hh -> Wp in FRAGMENT-TILED
//  layout (rows q=c*96+g*32+e_l) | [5888,5952) Ue | [5952,6016) Uo
// U packing (qc7): pair p -> j=p&3, ln=(p>>2)&63, h=p>>8; A-row float4 at
// l*4096 + (j*4+h)*256 + ln*4, B-row at +512 -> every qc U read is a
// contiguous 1KB wave-load.
__global__ __launch_bounds__(256) void prep_all(
    const float* __restrict__ embed, bf16_t* __restrict__ emb_hi,
    bf16_t* __restrict__ emb_lo, const float* __restrict__ W_ih,
    bf16_t* __restrict__ wih_hi, bf16_t* __restrict__ wih_lo,
    const float* __restrict__ Wc, bf16_t* __restrict__ wc_hi,
    bf16_t* __restrict__ wc_lo, const float* __restrict__ R_real,
    bf16_t* __restrict__ rr_hi, bf16_t* __restrict__ rr_lo,
    const float* __restrict__ R_imag, bf16_t* __restrict__ ri_hi,
    bf16_t* __restrict__ ri_lo, const float* __restrict__ W_hh,
    bf16_t* __restrict__ Wp_hi, bf16_t* __restrict__ Wp_lo,
    const float* __restrict__ phase, const float* __restrict__ th_e,
    const float* __restrict__ ph_e, const float* __restrict__ rh_e,
    float* __restrict__ Uep, const float* __restrict__ th_o,
    const float* __restrict__ ph_o, const float* __restrict__ rh_o,
    float* __restrict__ Uop) {
  const int bid = blockIdx.x, tid = threadIdx.x;
  if (bid < 512) {
    split_chunk(embed, emb_hi, emb_lo, bid, tid);
  } else if (bid < 1280) {
    split_chunk(W_ih, wih_hi, wih_lo, bid - 512, tid);
  } else if (bid < 2304) {
    split_chunk(Wc, wc_hi, wc_lo, bid - 1280, tid);
  } else if (bid < 3328) {
    split_chunk(R_real, rr_hi, rr_lo, bid - 2304, tid);
  } else if (bid < 4352) {
    split_chunk(R_imag, ri_hi, ri_lo, bid - 3328, tid);
  } else if (bid < 5888) {
    int q = bid - 4352;  // permuted row: q = c*96 + g*32 + e_l
    int c = q / 96, loc = q % 96;
    int g = loc >> 5, el = loc & 31;
    const float* src = &W_hh[(size_t)(g * 512 + c * 32 + el) * 512];
    if (tid < 64) {
      int k0 = tid * 8;
      float4 v0 = *(const float4*)&src[k0];
      float4 v1 = *(const float4*)&src[k0 + 4];
      float vv[8] = {v0.x, v0.y, v0.z, v0.w, v1.x, v1.y, v1.z, v1.w};
      bf16x8 h8, l8;
#pragma unroll
      for (int j = 0; j < 8; j++) {
        bf16_t h = (bf16_t)vv[j];
        h8[j] = h;
        l8[j] = (bf16_t)(vv[j] - (float)h);
      }
      size_t toff = tiled_off(q, k0);
      *(bf16x8*)&Wp_hi[toff] = h8;
      *(bf16x8*)&Wp_lo[toff] = l8;
    }
  } else if (bid < 5952) {
    int idx = (bid - 5888) * 256 + tid;
    if (idx < L_ * PE_) {
      int l = idx >> 9, p = idx & 511;
      float t = th_e[idx], pp = ph_e[idx], r = rh_e[idx];
      float c = cosf(t), s = sinf(t);
      float cp = cosf(pp), sp = sinf(pp), cr = cosf(r), sr = sinf(r);
      float u11r = c * (cp * cr - sp * sr), u11i = c * (cp * sr + sp * cr);
      float u12r = -s * sp, u12i = s * cp;
      float u21r = -s * sr, u21i = s * cr;
      float u22r = c, u22i = 0.0f;
      float f0 = phase[l * M_ + 2 * p], f1 = phase[l * M_ + 2 * p + 1];
      float c0 = cosf(f0), s0 = sinf(f0), c1 = cosf(f1), s1 = sinf(f1);
      float a, b;
      a = u11r * c0 - u11i * s0; b = u11r * s0 + u11i * c0; u11r = a; u11i = b;
      a = u21r * c0 - u21i * s0; b = u21r * s0 + u21i * c0; u21r = a; u21i = b;
      a = u12r * c1 - u12i * s1; b = u12r * s1 + u12i * c1; u12r = a; u12i = b;
      a = u22r * c1 - u22i * s1; b = u22r * s1 + u22i * c1; u22r = a; u22i = b;
      int j = p & 3, ln = (p >> 2) & 63, hh = p >> 8;
      size_t base = (size_t)l * 4096 + (size_t)(j * 4 + hh) * 256 + ln * 4;
      *(float4*)&Uep[base]       = make_float4(u11r, u11i, u12r, u12i);
      *(float4*)&Uep[base + 512] = make_float4(u21r, u21i, u22r, u22i);
    }
  } else {
    int idx = (bid - 5952) * 256 + tid;
    if (idx < L_ * PO_) {
      int l = idx / PO_, p = idx % PO_;
      float t = th_o[idx], pp = ph_o[idx], r = rh_o[idx];
      float c = cosf(t), s = sinf(t);
      float cp = cosf(pp), sp = sinf(pp), cr = cosf(r), sr = sinf(r);
      int j = p & 3, ln = (p >> 2) & 63, hh = p >> 8;
      size_t base = (size_t)l * 4096 + (size_t)(j * 4 + hh) * 256 + ln * 4;
      *(float4*)&Uop[base] = make_float4(c * (cp * cr - sp * sr),
                                         c * (cp * sr + sp * cr), -s * sp,
                                         s * cp);
      *(float4*)&Uop[base + 512] = make_float4(-s * sr, s * cr, c, 0.0f);
    }
  }
}

// ---------------------------------------------------------------- generic split GEMM
__global__ __launch_bounds__(256) void gemm_bt_mfma_split(
    const bf16_t* __restrict__ Ah, const bf16_t* __restrict__ Al,
    const bf16_t* __restrict__ Bh, const bf16_t* __restrict__ Bl,
    float* __restrict__ C, int Ndim, int K) {
  __shared__ bf16_t sAh[64 * 32], sAl[64 * 32], sBh[64 * 32], sBl[64 * 32];
  const int tid = threadIdx.x;
  const int m0 = blockIdx.y * 64, n0 = blockIdx.x * 64;
  const int wave = tid >> 6, lane = tid & 63;
  const int wr = wave >> 1, wc = wave & 1;
  const int quad = lane >> 4, l16 = lane & 15;
  f32x4 acc[2][2] = {};
  const int srow = tid >> 2, sk = (tid & 3) * 8;

  for (int k0 = 0; k0 < K; k0 += 32) {
    bf16x8 ah = *(const bf16x8*)&Ah[(size_t)(m0 + srow) * K + k0 + sk];
    bf16x8 al = *(const bf16x8*)&Al[(size_t)(m0 + srow) * K + k0 + sk];
    bf16x8 bh = *(const bf16x8*)&Bh[(size_t)(n0 + srow) * K + k0 + sk];
    bf16x8 bl = *(const bf16x8*)&Bl[(size_t)(n0 + srow) * K + k0 + sk];
    __syncthreads();
    *(bf16x8*)&sAh[srow * 32 + sk] = ah;
    *(bf16x8*)&sAl[srow * 32 + sk] = al;
    *(bf16x8*)&sBh[srow * 32 + sk] = bh;
    *(bf16x8*)&sBl[srow * 32 + sk] = bl;
    __syncthreads();
    bf16x8 fAh[2], fAl[2], fBh[2], fBl[2];
#pragma unroll
    for (int i = 0; i < 2; i++) {
      fAh[i] = *(const bf16x8*)&sAh[(wr * 32 + i * 16 + l16) * 32 + quad * 8];
      fAl[i] = *(const bf16x8*)&sAl[(wr * 32 + i * 16 + l16) * 32 + quad * 8];
      fBh[i] = *(const bf16x8*)&sBh[(wc * 32 + i * 16 + l16) * 32 + quad * 8];
      fBl[i] = *(const bf16x8*)&sBl[(wc * 32 + i * 16 + l16) * 32 + quad * 8];
    }
#pragma unroll
    for (int i = 0; i < 2; i++)
#pragma unroll
      for (int j = 0; j < 2; j++) {
        acc[i][j] = MFMA_BF16(fAh[i], fBh[j], acc[i][j], 0, 0, 0);
        acc[i][j] = MFMA_BF16(fAh[i], fBl[j], acc[i][j], 0, 0, 0);
        acc[i][j] = MFMA_BF16(fAl[i], fBh[j], acc[i][j], 0, 0, 0);
      }
  }
#pragma unroll
  for (int i = 0; i < 2; i++)
#pragma unroll
    for (int j = 0; j < 2; j++)
#pragma unroll
      for (int r = 0; r < 4; r++) {
        int row = wr * 32 + i * 16 + quad * 4 + r;
        int col = wc * 32 + j * 16 + l16;
        C[(size_t)(m0 + row) * Ndim + n0 + col] = acc[i][j][r];
      }
}

// ---------------------------------------------------------------- GRU step (v11: A direct, B via gload_lds dbuf)
// r8 lesson: per barrier interval, DMA bytes must be covered by that
// interval's MFMA work. This r7 structure (A direct vmcnt-pipelined, B DMA
// at BK=64 with 2 MFMA sub-steps of cover) is the measured family optimum.
__global__ __launch_bounds__(512) void gru_step11(
    const bf16_t* __restrict__ Hh, const bf16_t* __restrict__ Hl,
    const bf16_t* __restrict__ Wph, const bf16_t* __restrict__ Wpl,
    const int* __restrict__ tok, const float* __restrict__ eg,
    const float* __restrict__ b_ih, const float* __restrict__ b_hh,
    bf16_t* __restrict__ Oh, bf16_t* __restrict__ Ol, int t, int final_) {
  __shared__ bf16_t sB[2][2][24 * 512];   // [dbuf][group][hi:0-11|lo:12-23] 96KB
  __shared__ float sC[2][64 * 100];
  __shared__ float sbih[96], sbhh[96];
  const int tid = threadIdx.x;
  const int g = tid >> 8;                       // k-group (k in [g*256,(g+1)*256))
  const int gtid = tid & 255;
  const int ct = blockIdx.y, m0 = blockIdx.x * 64;  // bt fast, ct slow
  const int n0e = ct * 32;
  const int wg = gtid >> 6, lane = tid & 63;
  const int wr = wg >> 1, wc = wg & 1;
  const int quad = lane >> 4, l16 = lane & 15;

  // staging: 24 chunks/group/iter (12 hi + 12 lo), 6 per wave.
#define STAGE_B(buf, it)                                                      \
  {                                                                           \
    _Pragma("unroll") for (int r = 0; r < 6; r++) {                           \
      int c = wg * 6 + r;                                                     \
      int f = (c >= 12) ? (c - 12) : c;                                       \
      int j = f >> 1, ks = f & 1;                                             \
      const bf16_t* srcp = (c < 12) ? Wph : Wpl;                              \
      stage16b(&sB[buf][g][c * 512],                                          \
               &srcp[(size_t)(ct * 6 + j) * 8192 +                            \
                     (size_t)(g * 8 + (it) * 2 + ks) * 512 + lane * 8]);      \
    }                                                                         \
  }

  STAGE_B(0, 0);

  if (tid < 96) {
    sbih[tid] = b_ih[(tid >> 5) * 512 + n0e + (tid & 31)];
    sbhh[tid] = b_hh[(tid >> 5) * 512 + n0e + (tid & 31)];
  }

  float pir[4], piz[4], pin[4], phv[4];
#pragma unroll
  for (int u = 0; u < 4; u++) {
    int flat = u * 512 + tid;           // 0..2047 = 64 rows x 32 els
    int row = flat >> 5, el = flat & 31;
    int bb = m0 + row, eG = n0e + el;
    int tk = tok[bb * T_ + t];
    pir[u] = eg[(size_t)tk * G3_ + eG];
    piz[u] = eg[(size_t)tk * G3_ + 512 + eG];
    pin[u] = eg[(size_t)tk * G3_ + 1024 + eG];
    size_t toff = tiled_off(bb, eG);
    phv[u] = (float)Hh[toff] + (float)Hl[toff];
  }

  // A fragment bases (elements): frag (rt, kb) at rt*8192 + kb*512 + lane*8
  const size_t aB0 = (size_t)((m0 >> 4) + wr * 2 + 0) * 8192 + (size_t)g * 4096 + lane * 8;
  const size_t aB1 = (size_t)((m0 >> 4) + wr * 2 + 1) * 8192 + (size_t)g * 4096 + lane * 8;

  f32x4 acc[2][3] = {};
  __syncthreads();  // drain STAGE_B(0,0)
#pragma unroll
  for (int it = 0; it < 4; ++it) {
    const int buf = it & 1;
    if (it < 3) STAGE_B(buf ^ 1, it + 1);
    const bf16_t* sBg = &sB[buf][g][0];
#pragma unroll
    for (int ks2 = 0; ks2 < 2; ++ks2) {
      const int kb = it * 2 + ks2;      // within-group kb 0..7 ascending
      const int ko = kb * 512;
      bf16x8 fah[2], fal[2], fbh[3], fbl[3];
      fah[0] = *(const bf16x8*)&Hh[aB0 + ko];
      fah[1] = *(const bf16x8*)&Hh[aB1 + ko];
      fal[0] = *(const bf16x8*)&Hl[aB0 + ko];
      fal[1] = *(const bf16x8*)&Hl[aB1 + ko];
#pragma unroll
      for (int j = 0; j < 3; j++) {
        int f = (wc * 3 + j) * 2 + ks2;
        fbh[j] = *(const bf16x8*)&sBg[f * 512 + lane * 8];
        fbl[j] = *(const bf16x8*)&sBg[(f + 12) * 512 + lane * 8];
      }
#pragma unroll
      for (int i = 0; i < 2; i++)
#pragma unroll
        for (int j = 0; j < 3; j++) {
          acc[i][j] = MFMA_BF16(fah[i], fbh[j], acc[i][j], 0, 0, 0);
          acc[i][j] = MFMA_BF16(fah[i], fbl[j], acc[i][j], 0, 0, 0);
          acc[i][j] = MFMA_BF16(fal[i], fbh[j], acc[i][j], 0, 0, 0);
        }
    }
    __syncthreads();  // drains next-iter DMA; protects buf reuse
  }
#undef STAGE_B
#pragma unroll
  for (int i = 0; i < 2; i++)
#pragma unroll
    for (int j = 0; j < 3; j++)
#pragma unroll
      for (int r = 0; r < 4; r++)
        sC[g][(wr * 32 + i * 16 + quad * 4 + r) * 100 + wc * 48 + j * 16 + l16] =
            acc[i][j][r];
  __syncthreads();
#pragma unroll
  for (int u = 0; u < 4; u++) {
    int flat = u * 512 + tid;
    int row = flat >> 5, el = flat & 31;
    int bb = m0 + row, eG = n0e + el;
    float ir = pir[u] + sbih[el];
    float iz = piz[u] + sbih[32 + el];
    float in_ = pin[u] + sbih[64 + el];
    float hr = sC[0][row * 100 + el] + sC[1][row * 100 + el] + sbhh[el];
    float hz = sC[0][row * 100 + 32 + el] + sC[1][row * 100 + 32 + el] + sbhh[32 + el];
    float hn = sC[0][row * 100 + 64 + el] + sC[1][row * 100 + 64 + el] + sbhh[64 + el];
    float r = 1.0f / (1.0f + __expf(-(ir + hr)));
    float z = 1.0f / (1.0f + __expf(-(iz + hz)));
    float targ = fminf(fmaxf(in_ + r * hn, -15.0f), 15.0f);
    float e2 = __expf(2.0f * targ);
    float n = (e2 - 1.0f) / (e2 + 1.0f);
    float hnew = (1.0f - z) * n + z * phv[u];
    bf16_t hh = (bf16_t)hnew;
    bf16_t ll = (bf16_t)(hnew - (float)hh);
    if (final_) {
      size_t hidx = (size_t)bb * 512 + eG;  // row-major for zc GEMM
      Oh[hidx] = hh;
      Ol[hidx] = ll;
    } else {
      size_t toff = tiled_off(bb, eG);
      Oh[toff] = hh;
      Ol[toff] = ll;
    }
  }
}

// ---------------------------------------------------------------- MZI core (qc7: direct-global U reads, no staging)
// r10 measured 47us (vs 58-64 staged): the staged-DMA drain barrier was the
// pacer. r11 lesson: U dedup (2 b's/wave) trades wave count 1:1 — 512 waves
// = 0.5/SIMD collapsed to 173us. qc7's point (2048 waves, 2x dup) is the
// measured optimum of the parallelism-vs-duplication curve.
__device__ inline void apply_u(float4 A, float4 Bv, float& x0r, float& x0i,
                               float& x1r, float& x1i) {
  float n0r = A.x * x0r - A.y * x0i + A.z * x1r - A.w * x1i;
  float n0i = A.x * x0i + A.y * x0r + A.z * x1i + A.w * x1r;
  float n1r = Bv.x * x0r - Bv.y * x0i + Bv.z * x1r - Bv.w * x1i;
  float n1i = Bv.x * x0i + Bv.y * x0r + Bv.z * x1i + Bv.w * x1r;
  x0r = n0r; x0i = n0i; x1r = n1r; x1i = n1i;
}

__global__ __launch_bounds__(256) void qc7(
    const float* __restrict__ zc, const float* __restrict__ bc,
    const float* __restrict__ Uep, const float* __restrict__ Uop,
    bf16_t* __restrict__ prh, bf16_t* __restrict__ prl,
    bf16_t* __restrict__ pih, bf16_t* __restrict__ pil) {
  __shared__ float sred[4];
  __shared__ float4 sEx[2][2][2];  // [layer parity][b-in-block][0:h0.l63 | 1:h1.l0]
  const int tid = threadIdx.x;
  const int wave = tid >> 6, lane = tid & 63;
  const int wb = wave >> 1, h = wave & 1;
  const int b = blockIdx.x * 2 + wb;
  const int e0 = h * 512 + lane * 8;

  float xr[8], xi[8];
  {
    const float4* zr4 = (const float4*)&zc[(size_t)b * M2_ + e0];
    const float4* zi4 = (const float4*)&zc[(size_t)b * M2_ + M_ + e0];
    const float4* br4 = (const float4*)&bc[e0];
    const float4* bi4 = (const float4*)&bc[M_ + e0];
#pragma unroll
    for (int q = 0; q < 2; q++) {
      float4 a = zr4[q], bb = br4[q];
      xr[4 * q + 0] = a.x + bb.x; xr[4 * q + 1] = a.y + bb.y;
      xr[4 * q + 2] = a.z + bb.z; xr[4 * q + 3] = a.w + bb.w;
      float4 c2 = zi4[q], d = bi4[q];
      xi[4 * q + 0] = c2.x + d.x; xi[4 * q + 1] = c2.y + d.y;
      xi[4 * q + 2] = c2.z + d.z; xi[4 * q + 3] = c2.w + d.w;
    }
  }
  {
    float s = 0.0f;
#pragma unroll
    for (int k = 0; k < 8; k++) s += xr[k] * xr[k] + xi[k] * xi[k];
    for (int off = 32; off; off >>= 1) s += __shfl_xor(s, off);
    if (lane == 0) sred[wave] = s;
    __syncthreads();
    float inv = 1.0f / sqrtf(sred[2 * wb] + sred[2 * wb + 1] + 1e-8f);
#pragma unroll
    for (int k = 0; k < 8; k++) { xr[k] *= inv; xi[k] *= inv; }
  }
  if (h == 0 && lane == 63) sEx[0][wb][0] = make_float4(xr[6], xi[6], xr[7], xi[7]);
  if (h == 1 && lane == 0)  sEx[0][wb][1] = make_float4(xr[0], xi[0], xr[1], xi[1]);
  __syncthreads();

#pragma unroll 1
  for (int l = 0; l < L_; ++l) {
    const int buf = l & 1;
    const float* Ub = &Uep[(size_t)l * 4096];
    const float* Ob = &Uop[(size_t)l * 4096];
    // issue ALL U loads first (16 x 1KB contiguous wave-loads in flight)
    float4 eA[4], eB[4], oA[3], oB[3], A3, B3;
#pragma unroll
    for (int j = 0; j < 4; j++) {
      eA[j] = *(const float4*)&Ub[(j * 4 + h) * 256 + lane * 4];
      eB[j] = *(const float4*)&Ub[(j * 4 + 2 + h) * 256 + lane * 4];
    }
#pragma unroll
    for (int j = 0; j < 3; j++) {
      oA[j] = *(const float4*)&Ob[(j * 4 + h) * 256 + lane * 4];
      oB[j] = *(const float4*)&Ob[(j * 4 + 2 + h) * 256 + lane * 4];
    }
    A3 = *(const float4*)&Ob[(12 + h) * 256 + lane * 4];
    B3 = *(const float4*)&Ob[(14 + h) * 256 + lane * 4];
    // partner pre-layer boundary values (written end of previous layer)
    float4 par = make_float4(0.f, 0.f, 0.f, 0.f);
    if (h == 0 && lane == 63) par = sEx[buf][wb][1];  // h1.l0's (x0,x1)
    if (h == 1 && lane == 0)  par = sEx[buf][wb][0];  // h0.l63's (x6,x7)
    // even pass: 4 lane-local pairs
#pragma unroll
    for (int j = 0; j < 4; j++)
      apply_u(eA[j], eB[j], xr[2 * j], xi[2 * j], xr[2 * j + 1], xi[2 * j + 1]);
    // redundantly recompute partner's post-even boundary value
    float exr = 0.f, exi = 0.f;
    if (h == 0 && lane == 63) {
      float4 Ae = *(const float4*)&Ub[1 * 256];  // even p=256 A-row (j=0,h=1)
      exr = Ae.x * par.x - Ae.y * par.y + Ae.z * par.z - Ae.w * par.w;
      exi = Ae.x * par.y + Ae.y * par.x + Ae.z * par.w + Ae.w * par.z;
    }
    if (h == 1 && lane == 0) {
      float4 Be = *(const float4*)&Ub[14 * 256 + 252];  // even p=255 B-row (j=3,h=0)
      exr = Be.x * par.x - Be.y * par.y + Be.z * par.z - Be.w * par.w;
      exi = Be.x * par.y + Be.y * par.x + Be.z * par.w + Be.w * par.z;
    }
    // odd pass: 3 interior lane-local pairs
#pragma unroll
    for (int j = 0; j < 3; j++)
      apply_u(oA[j], oB[j], xr[2 * j + 1], xi[2 * j + 1], xr[2 * j + 2],
              xi[2 * j + 2]);
    // boundary pair j=3: (x[7], next element)
    float nr = __shfl_down(xr[0], 1), ni = __shfl_down(xi[0], 1);
    if (h == 0 && lane == 63) { nr = exr; ni = exi; }  // cross-wave v1
    float srr = 0.f, sii = 0.f;
    if (!(h == 1 && lane == 63)) {  // (1023,1024) doesn't exist
      float n0r = A3.x * xr[7] - A3.y * xi[7] + A3.z * nr - A3.w * ni;
      float n0i = A3.x * xi[7] + A3.y * xr[7] + A3.z * ni + A3.w * nr;
      srr = B3.x * xr[7] - B3.y * xi[7] + B3.z * nr - B3.w * ni;
      sii = B3.x * xi[7] + B3.y * xr[7] + B3.z * ni + B3.w * nr;
      xr[7] = n0r; xi[7] = n0i;
    }
    float nx0r = 0.f, nx0i = 0.f;
    if (h == 1 && lane == 0) {  // cross pair q=255: v0=partner(ex), v1=own x[0]
      float4 Bc = *(const float4*)&Ob[14 * 256 + 252];  // odd q=255 B-row
      nx0r = Bc.x * exr - Bc.y * exi + Bc.z * xr[0] - Bc.w * xi[0];
      nx0i = Bc.x * exi + Bc.y * exr + Bc.z * xi[0] + Bc.w * xr[0];
    }
    float rr = __shfl_up(srr, 1), ri2 = __shfl_up(sii, 1);
    if (lane > 0) { xr[0] = rr; xi[0] = ri2; }
    if (h == 1 && lane == 0) { xr[0] = nx0r; xi[0] = nx0i; }
    // publish boundary values for next layer (parity-buffered: no race)
    if (h == 0 && lane == 63)
      sEx[1 - buf][wb][0] = make_float4(xr[6], xi[6], xr[7], xi[7]);
    if (h == 1 && lane == 0)
      sEx[1 - buf][wb][1] = make_float4(xr[0], xi[0], xr[1], xi[1]);
    __syncthreads();  // sEx exchange visibility only (no DMA drain)
  }
  size_t base = (size_t)b * M_ + e0;
  bf16x8 vh, vl, wh, wl;
#pragma unroll
  for (int k = 0; k < 8; k++) {
    float vr = xr[k], vi = xi[k];
    bf16_t h1 = (bf16_t)vr;
    vh[k] = h1; vl[k] = (bf16_t)(vr - (float)h1);
    bf16_t h2 = (bf16_t)vi;
    wh[k] = h2; wl[k] = (bf16_t)(vi - (float)h2);
  }
  *(bf16x8*)&prh[base] = vh;
  *(bf16x8*)&prl[base] = vl;
  *(bf16x8*)&pih[base] = wh;
  *(bf16x8*)&pil[base] = wl;
}

// ---------------------------------------------------------------- readout (r7 known-good)
// r9 lesson: K-split pays only when MFMA-per-interval is thin; readout has
// 48 MFMA/interval (compute-covered at 1 wave/SIMD).
__global__ __launch_bounds__(256) void readout_mfma(
    const bf16_t* __restrict__ Arh, const bf16_t* __restrict__ Arl,
    const bf16_t* __restrict__ Aih, const bf16_t* __restrict__ Ail,
    const bf16_t* __restrict__ Brh, const bf16_t* __restrict__ Brl,
    const bf16_t* __restrict__ Bih, const bf16_t* __restrict__ Bil,
    float* __restrict__ out) {
  __shared__ bf16_t sArh[64 * 32], sArl[64 * 32], sAih[64 * 32], sAil[64 * 32];
  __shared__ bf16_t sBrh[64 * 32], sBrl[64 * 32], sBih[64 * 32], sBil[64 * 32];
  const int tid = threadIdx.x;
  const int b0 = blockIdx.y * 64, v0 = blockIdx.x * 64;
  const int wave = tid >> 6, lane = tid & 63;
  const int wr = wave >> 1, wc = wave & 1;
  const int quad = lane >> 4, l16 = lane & 15;
  f32x4 aP[2][2] = {}, aQ[2][2] = {}, aI[2][2] = {};
  const int srow = tid >> 2, sk = (tid & 3) * 8;

  for (int k0 = 0; k0 < M_; k0 += 32) {
    size_t aoff = (size_t)(b0 + srow) * M_ + k0 + sk;
    size_t boff = (size_t)(v0 + srow) * M_ + k0 + sk;
    bf16x8 v0r = *(const bf16x8*)&Arh[aoff];
    bf16x8 v1r = *(const bf16x8*)&Arl[aoff];
    bf16x8 v2r = *(const bf16x8*)&Aih[aoff];
    bf16x8 v3r = *(const bf16x8*)&Ail[aoff];
    bf16x8 v4r = *(const bf16x8*)&Brh[boff];
    bf16x8 v5r = *(const bf16x8*)&Brl[boff];
    bf16x8 v6r = *(const bf16x8*)&Bih[boff];
    bf16x8 v7r = *(const bf16x8*)&Bil[boff];
    __syncthreads();
    *(bf16x8*)&sArh[srow * 32 + sk] = v0r;
    *(bf16x8*)&sArl[srow * 32 + sk] = v1r;
    *(bf16x8*)&sAih[srow * 32 + sk] = v2r;
    *(bf16x8*)&sAil[srow * 32 + sk] = v3r;
    *(bf16x8*)&sBrh[srow * 32 + sk] = v4r;
    *(bf16x8*)&sBrl[srow * 32 + sk] = v5r;
    *(bf16x8*)&sBih[srow * 32 + sk] = v6r;
    *(bf16x8*)&sBil[srow * 32 + sk] = v7r;
    __syncthreads();
    bf16x8 fArh[2], fArl[2], fAih[2], fAil[2], fBrh[2], fBrl[2], fBih[2], fBil[2];
#pragma unroll
    for (int i = 0; i < 2; i++) {
      int ra = (wr * 32 + i * 16 + l16) * 32 + quad * 8;
      int rb = (wc * 32 + i * 16 + l16) * 32 + quad * 8;
      fArh[i] = *(const bf16x8*)&sArh[ra];
      fArl[i] = *(const bf16x8*)&sArl[ra];
      fAih[i] = *(const bf16x8*)&sAih[ra];
      fAil[i] = *(const bf16x8*)&sAil[ra];
      fBrh[i] = *(const bf16x8*)&sBrh[rb];
      fBrl[i] = *(const bf16x8*)&sBrl[rb];
      fBih[i] = *(const bf16x8*)&sBih[rb];
      fBil[i] = *(const bf16x8*)&sBil[rb];
    }
#pragma unroll
    for (int i = 0; i < 2; i++)
#pragma unroll
      for (int j = 0; j < 2; j++) {
        aP[i][j] = MFMA_BF16(fArh[i], fBrh[j], aP[i][j], 0, 0, 0);
        aP[i][j] = MFMA_BF16(fArh[i], fBrl[j], aP[i][j], 0, 0, 0);
        aP[i][j] = MFMA_BF16(fArl[i], fBrh[j], aP[i][j], 0, 0, 0);
        aQ[i][j] = MFMA_BF16(fAih[i], fBih[j], aQ[i][j], 0, 0, 0);
        aQ[i][j] = MFMA_BF16(fAih[i], fBil[j], aQ[i][j], 0, 0, 0);
        aQ[i][j] = MFMA_BF16(fAil[i], fBih[j], aQ[i][j], 0, 0, 0);
        aI[i][j] = MFMA_BF16(fArh[i], fBih[j], aI[i][j], 0, 0, 0);
        aI[i][j] = MFMA_BF16(fArh[i], fBil[j], aI[i][j], 0, 0, 0);
        aI[i][j] = MFMA_BF16(fArl[i], fBih[j], aI[i][j], 0, 0, 0);
        aI[i][j] = MFMA_BF16(fAih[i], fBrh[j], aI[i][j], 0, 0, 0);
        aI[i][j] = MFMA_BF16(fAih[i], fBrl[j], aI[i][j], 0, 0, 0);
        aI[i][j] = MFMA_BF16(fAil[i], fBrh[j], aI[i][j], 0, 0, 0);
      }
  }
#pragma unroll
  for (int i = 0; i < 2; i++)
#pragma unroll
    for (int j = 0; j < 2; j++)
#pragma unroll
      for (int r = 0; r < 4; r++) {
        int row = wr * 32 + i * 16 + quad * 4 + r;
        int col = wc * 32 + j * 16 + l16;
        float re = aP[i][j][r] - aQ[i][j][r];
        float im = aI[i][j][r];
        out[(size_t)(b0 + row) * V_ + v0 + col] = logf(re * re + im * im + 1e-12f);
      }
}

// ---------------------------------------------------------------- logsumexp
__global__ __launch_bounds__(256) void lse_kernel(float* __restrict__ out) {
  __shared__ float redm[4], reds[4];
  const int b = blockIdx.x, t = threadIdx.x;
  float4 v = *(float4*)&out[(size_t)b * V_ + 4 * t];
  float mx = fmaxf(fmaxf(v.x, v.y), fmaxf(v.z, v.w));
  for (int off = 32; off; off >>= 1) mx = fmaxf(mx, __shfl_down(mx, off, 64));
  if ((t & 63) == 0) redm[t >> 6] = mx;
  __syncthreads();
  mx = fmaxf(fmaxf(redm[0], redm[1]), fmaxf(redm[2], redm[3]));
  float s = expf(v.x - mx) + expf(v.y - mx) + expf(v.z - mx) + expf(v.w - mx);
  for (int off = 32; off; off >>= 1) s += __shfl_down(s, off, 64);
  if ((t & 63) == 0) reds[t >> 6] = s;
  __syncthreads();
  s = reds[0] + reds[1] + reds[2] + reds[3];
  float lse = mx + logf(s);
  v.x -= lse; v.y -= lse; v.z -= lse; v.w -= lse;
  *(float4*)&out[(size_t)b * V_ + 4 * t] = v;
}

// ---------------------------------------------------------------- launch
extern "C" void kernel_launch(void* const* d_in, const int* in_sizes, int n_in,
                              void* d_out, int out_size, void* d_ws, size_t ws_size,
                              hipStream_t stream) {
  const int*   tokens = (const int*)d_in[0];
  const float* embed  = (const float*)d_in[1];
  const float* W_ih   = (const float*)d_in[2];
  const float* W_hh   = (const float*)d_in[3];
  const float* b_ih   = (const float*)d_in[4];
  const float* b_hh   = (const float*)d_in[5];
  const float* Wc     = (const float*)d_in[6];
  const float* bc     = (const float*)d_in[7];
  const float* phase  = (const float*)d_in[8];
  const float* theta_e = (const float*)d_in[9];
  const float* phi_e  = (const float*)d_in[10];
  const float* rho_e  = (const float*)d_in[11];
  const float* theta_o = (const float*)d_in[12];
  const float* phi_o  = (const float*)d_in[13];
  const float* rho_o  = (const float*)d_in[14];
  const float* R_real = (const float*)d_in[15];
  const float* R_imag = (const float*)d_in[16];
  float* out = (float*)d_out;

  char* w = (char*)d_ws;
  auto alloc = [&](size_t bytes) -> void* {
    void* p = (void*)w;
    w += (bytes + 255) & ~(size_t)255;
    return p;
  };
  // region0: weight splits; later aliased by psi hi/lo (dead by then)
  char* region0 = w;
  bf16_t* emb_hi = (bf16_t*)alloc((size_t)V_ * E_ * 2);
  bf16_t* emb_lo = (bf16_t*)alloc((size_t)V_ * E_ * 2);
  bf16_t* wih_hi = (bf16_t*)alloc((size_t)G3_ * E_ * 2);
  bf16_t* wih_lo = (bf16_t*)alloc((size_t)G3_ * E_ * 2);
  bf16_t* wc_hi  = (bf16_t*)alloc((size_t)M2_ * E_ * 2);
  bf16_t* wc_lo  = (bf16_t*)alloc((size_t)M2_ * E_ * 2);
  // region1: eg + Wp; later aliased by zc
  char* region1 = w;
  float*  eg     = (float*)alloc((size_t)V_ * G3_ * 4);
  bf16_t* Wp_hi  = (bf16_t*)alloc((size_t)G3_ * E_ * 2);
  bf16_t* Wp_lo  = (bf16_t*)alloc((size_t)G3_ * E_ * 2);
  // persistent
  bf16_t* h0_hi = (bf16_t*)alloc((size_t)B_ * E_ * 2);
  bf16_t* h0_lo = (bf16_t*)alloc((size_t)B_ * E_ * 2);
  bf16_t* h1_hi = (bf16_t*)alloc((size_t)B_ * E_ * 2);
  bf16_t* h1_lo = (bf16_t*)alloc((size_t)B_ * E_ * 2);
  bf16_t* rr_hi = (bf16_t*)alloc((size_t)V_ * M_ * 2);
  bf16_t* rr_lo = (bf16_t*)alloc((size_t)V_ * M_ * 2);
  bf16_t* ri_hi = (bf16_t*)alloc((size_t)V_ * M_ * 2);
  bf16_t* ri_lo = (bf16_t*)alloc((size_t)V_ * M_ * 2);
  float*  Uep   = (float*)alloc((size_t)L_ * 4096 * 4);
  float*  Uop   = (float*)alloc((size_t)L_ * 4096 * 4);

  // aliases
  float*  zc  = (float*)region1;
  bf16_t* prh = (bf16_t*)(region0 + 0 * 2097152);
  bf16_t* prl = (bf16_t*)(region0 + 1 * 2097152);
  bf16_t* pih = (bf16_t*)(region0 + 2 * 2097152);
  bf16_t* pil = (bf16_t*)(region0 + 3 * 2097152);

  hipMemsetAsync(h0_hi, 0, (size_t)B_ * E_ * 2 * 2, stream);

  // ONE fused prep launch
  prep_all<<<6016, 256, 0, stream>>>(
      embed, emb_hi, emb_lo, W_ih, wih_hi, wih_lo, Wc, wc_hi, wc_lo, R_real,
      rr_hi, rr_lo, R_imag, ri_hi, ri_lo, W_hh, Wp_hi, Wp_lo, phase, theta_e,
      phi_e, rho_e, Uep, theta_o, phi_o, rho_o, Uop);

  // eg = embed @ W_ih^T  (V x 3E)
  {
    dim3 grid(G3_ / 64, V_ / 64);
    gemm_bt_mfma_split<<<grid, 256, 0, stream>>>(emb_hi, emb_lo, wih_hi, wih_lo,
                                                 eg, G3_, E_);
  }

  // GRU: 64 per-step launches; A direct tiled, B via gload_lds dbuf (r7 opt)
  for (int t = 0; t < T_; ++t) {
    const bf16_t* ih = (t & 1) ? h1_hi : h0_hi;
    const bf16_t* il = (t & 1) ? h1_lo : h0_lo;
    bf16_t* oh = (t & 1) ? h0_hi : h1_hi;
    bf16_t* ol = (t & 1) ? h0_lo : h1_lo;
    dim3 grid(16, 16);  // bt fast, ct slow (L2 locality)
    gru_step11<<<grid, 512, 0, stream>>>(ih, il, Wp_hi, Wp_lo, tokens, eg,
                                         b_ih, b_hh, oh, ol, t,
                                         (t == T_ - 1) ? 1 : 0);
  }

  // zc = h @ Wc^T  (B x 2M); final h (row-major) in buffer 0 after t=63
  {
    dim3 grid(M2_ / 64, B_ / 64);
    gemm_bt_mfma_split<<<grid, 256, 0, stream>>>(h0_hi, h0_lo, wc_hi, wc_lo,
                                                 zc, M2_, E_);
  }

  // MZI stack (qc7: direct-global U reads, no staging)
  qc7<<<B_ / 2, 256, 0, stream>>>(zc, bc, Uep, Uop, prh, prl, pih, pil);

  // readout (r7 known-good)
  {
    dim3 grid(V_ / 64, B_ / 64);
    readout_mfma<<<grid, 256, 0, stream>>>(prh, prl, pih, pil, rr_hi, rr_lo,
                                           ri_hi, ri_lo, out);
  }

  // logsumexp
  lse_kernel<<<B_, 256, 0, stream>>>(out);
}

// Round 13
// 830.313 us; speedup vs baseline: 1.1638x; 1.0155x over previous
//
#include <hip/hip_runtime.h>
#include <math.h>

typedef __bf16 bf16_t;
typedef bf16_t bf16x8 __attribute__((ext_vector_type(8)));
typedef bf16_t bf16x4 __attribute__((ext_vector_type(4)));
typedef float  f32x4  __attribute__((ext_vector_type(4)));

#define B_  1024
#define T_  64
#define V_  1024
#define E_  512
#define M_  1024
#define L_  32
#define PE_ 512
#define PO_ 511
#define G3_ 1536
#define M2_ 2048

#define MFMA_BF16 __builtin_amdgcn_mfma_f32_16x16x32_bf16

// async global->LDS: dest = wave-uniform base + lane*16
__device__ __forceinline__ void stage16b(bf16_t* lds_base, const bf16_t* gsrc) {
  __builtin_amdgcn_global_load_lds(
      (const __attribute__((address_space(1))) unsigned int*)gsrc,
      (__attribute__((address_space(3))) unsigned int*)lds_base, 16, 0, 0);
}

// fragment-tiled layout: matrix [R][512] stored as 16x32 tiles in MFMA-frag
// order. Element (row,k) at ((row>>4)*16 + (k>>5))*512 + ((k>>3)&3)*128 +
// (row&15)*8 + (k&7)  [elements]. A wave's frag load (16 rows x 32 k) is then
// base + lane*8 elems = contiguous 1KB. 4-runs with k%8 in {0,4} stay
// contiguous (used by the vectorized GRU prologue/epilogue).
__device__ __forceinline__ size_t tiled_off(int row, int k) {
  return ((size_t)(row >> 4) * 16 + (k >> 5)) * 512 +
         (size_t)(((k >> 3) & 3) * 16 + (row & 15)) * 8 + (k & 7);
}

// ---------------------------------------------------------------- prep (fused)
__device__ __forceinline__ void split_chunk(const float* __restrict__ src,
                                            bf16_t* __restrict__ hi,
                                            bf16_t* __restrict__ lo, int blk,
                                            int tid) {
  int i4 = (blk * 256 + tid) * 4;
  float4 v = *(const float4*)&src[i4];
  float vv[4] = {v.x, v.y, v.z, v.w};
#pragma unroll
  for (int j = 0; j < 4; j++) {
    bf16_t h = (bf16_t)vv[j];
    hi[i4 + j] = h;
    lo[i4 + j] = (bf16_t)(vv[j] - (float)h);
  }
}

// Block ranges:
//  [0,512) embed | [512,1280) W_ih | [1280,2304) Wc | [2304,3328) R_real |
//  [3328,4352) R_imag | [4352,5888) permute W_hh -> Wp in FRAGMENT-TILED
//  layout (rows q=c*96+g*32+e_l) | [5888,5952) Ue | [5952,6016) Uo
// U packing (qc7): pair p -> j=p&3, ln=(p>>2)&63, h=p>>8; A-row float4 at
// l*4096 + (j*4+h)*256 + ln*4, B-row at +512 -> every qc U read is a
// contiguous 1KB wave-load.
__global__ __launch_bounds__(256) void prep_all(
    const float* __restrict__ embed, bf16_t* __restrict__ emb_hi,
    bf16_t* __restrict__ emb_lo, const float* __restrict__ W_ih,
    bf16_t* __restrict__ wih_hi, bf16_t* __restrict__ wih_lo,
    const float* __restrict__ Wc, bf16_t* __restrict__ wc_hi,
    bf16_t* __restrict__ wc_lo, const float* __restrict__ R_real,
    bf16_t* __restrict__ rr_hi, bf16_t* __restrict__ rr_lo,
    const float* __restrict__ R_imag, bf16_t* __restrict__ ri_hi,
    bf16_t* __restrict__ ri_lo, const float* __restrict__ W_hh,
    bf16_t* __restrict__ Wp_hi, bf16_t* __restrict__ Wp_lo,
    const float* __restrict__ phase, const float* __restrict__ th_e,
    const float* __restrict__ ph_e, const float* __restrict__ rh_e,
    float* __restrict__ Uep, const float* __restrict__ th_o,
    const float* __restrict__ ph_o, const float* __restrict__ rh_o,
    float* __restrict__ Uop) {
  const int bid = blockIdx.x, tid = threadIdx.x;
  if (bid < 512) {
    split_chunk(embed, emb_hi, emb_lo, bid, tid);
  } else if (bid < 1280) {
    split_chunk(W_ih, wih_hi, wih_lo, bid - 512, tid);
  } else if (bid < 2304) {
    split_chunk(Wc, wc_hi, wc_lo, bid - 1280, tid);
  } else if (bid < 3328) {
    split_chunk(R_real, rr_hi, rr_lo, bid - 2304, tid);
  } else if (bid < 4352) {
    split_chunk(R_imag, ri_hi, ri_lo, bid - 3328, tid);
  } else if (bid < 5888) {
    int q = bid - 4352;  // permuted row: q = c*96 + g*32 + e_l
    int c = q / 96, loc = q % 96;
    int g = loc >> 5, el = loc & 31;
    const float* src = &W_hh[(size_t)(g * 512 + c * 32 + el) * 512];
    if (tid < 64) {
      int k0 = tid * 8;
      float4 v0 = *(const float4*)&src[k0];
      float4 v1 = *(const float4*)&src[k0 + 4];
      float vv[8] = {v0.x, v0.y, v0.z, v0.w, v1.x, v1.y, v1.z, v1.w};
      bf16x8 h8, l8;
#pragma unroll
      for (int j = 0; j < 8; j++) {
        bf16_t h = (bf16_t)vv[j];
        h8[j] = h;
        l8[j] = (bf16_t)(vv[j] - (float)h);
      }
      size_t toff = tiled_off(q, k0);
      *(bf16x8*)&Wp_hi[toff] = h8;
      *(bf16x8*)&Wp_lo[toff] = l8;
    }
  } else if (bid < 5952) {
    int idx = (bid - 5888) * 256 + tid;
    if (idx < L_ * PE_) {
      int l = idx >> 9, p = idx & 511;
      float t = th_e[idx], pp = ph_e[idx], r = rh_e[idx];
      float c = cosf(t), s = sinf(t);
      float cp = cosf(pp), sp = sinf(pp), cr = cosf(r), sr = sinf(r);
      float u11r = c * (cp * cr - sp * sr), u11i = c * (cp * sr + sp * cr);
      float u12r = -s * sp, u12i = s * cp;
      float u21r = -s * sr, u21i = s * cr;
      float u22r = c, u22i = 0.0f;
      float f0 = phase[l * M_ + 2 * p], f1 = phase[l * M_ + 2 * p + 1];
      float c0 = cosf(f0), s0 = sinf(f0), c1 = cosf(f1), s1 = sinf(f1);
      float a, b;
      a = u11r * c0 - u11i * s0; b = u11r * s0 + u11i * c0; u11r = a; u11i = b;
      a = u21r * c0 - u21i * s0; b = u21r * s0 + u21i * c0; u21r = a; u21i = b;
      a = u12r * c1 - u12i * s1; b = u12r * s1 + u12i * c1; u12r = a; u12i = b;
      a = u22r * c1 - u22i * s1; b = u22r * s1 + u22i * c1; u22r = a; u22i = b;
      int j = p & 3, ln = (p >> 2) & 63, hh = p >> 8;
      size_t base = (size_t)l * 4096 + (size_t)(j * 4 + hh) * 256 + ln * 4;
      *(float4*)&Uep[base]       = make_float4(u11r, u11i, u12r, u12i);
      *(float4*)&Uep[base + 512] = make_float4(u21r, u21i, u22r, u22i);
    }
  } else {
    int idx = (bid - 5952) * 256 + tid;
    if (idx < L_ * PO_) {
      int l = idx / PO_, p = idx % PO_;
      float t = th_o[idx], pp = ph_o[idx], r = rh_o[idx];
      float c = cosf(t), s = sinf(t);
      float cp = cosf(pp), sp = sinf(pp), cr = cosf(r), sr = sinf(r);
      int j = p & 3, ln = (p >> 2) & 63, hh = p >> 8;
      size_t base = (size_t)l * 4096 + (size_t)(j * 4 + hh) * 256 + ln * 4;
      *(float4*)&Uop[base] = make_float4(c * (cp * cr - sp * sr),
                                         c * (cp * sr + sp * cr), -s * sp,
                                         s * cp);
      *(float4*)&Uop[base + 512] = make_float4(-s * sr, s * cr, c, 0.0f);
    }
  }
}

// ---------------------------------------------------------------- generic split GEMM
__global__ __launch_bounds__(256) void gemm_bt_mfma_split(
    const bf16_t* __restrict__ Ah, const bf16_t* __restrict__ Al,
    const bf16_t* __restrict__ Bh, const bf16_t* __restrict__ Bl,
    float* __restrict__ C, int Ndim, int K) {
  __shared__ bf16_t sAh[64 * 32], sAl[64 * 32], sBh[64 * 32], sBl[64 * 32];
  const int tid = threadIdx.x;
  const int m0 = blockIdx.y * 64, n0 = blockIdx.x * 64;
  const int wave = tid >> 6, lane = tid & 63;
  const int wr = wave >> 1, wc = wave & 1;
  const int quad = lane >> 4, l16 = lane & 15;
  f32x4 acc[2][2] = {};
  const int srow = tid >> 2, sk = (tid & 3) * 8;

  for (int k0 = 0; k0 < K; k0 += 32) {
    bf16x8 ah = *(const bf16x8*)&Ah[(size_t)(m0 + srow) * K + k0 + sk];
    bf16x8 al = *(const bf16x8*)&Al[(size_t)(m0 + srow) * K + k0 + sk];
    bf16x8 bh = *(const bf16x8*)&Bh[(size_t)(n0 + srow) * K + k0 + sk];
    bf16x8 bl = *(const bf16x8*)&Bl[(size_t)(n0 + srow) * K + k0 + sk];
    __syncthreads();
    *(bf16x8*)&sAh[srow * 32 + sk] = ah;
    *(bf16x8*)&sAl[srow * 32 + sk] = al;
    *(bf16x8*)&sBh[srow * 32 + sk] = bh;
    *(bf16x8*)&sBl[srow * 32 + sk] = bl;
    __syncthreads();
    bf16x8 fAh[2], fAl[2], fBh[2], fBl[2];
#pragma unroll
    for (int i = 0; i < 2; i++) {
      fAh[i] = *(const bf16x8*)&sAh[(wr * 32 + i * 16 + l16) * 32 + quad * 8];
      fAl[i] = *(const bf16x8*)&sAl[(wr * 32 + i * 16 + l16) * 32 + quad * 8];
      fBh[i] = *(const bf16x8*)&sBh[(wc * 32 + i * 16 + l16) * 32 + quad * 8];
      fBl[i] = *(const bf16x8*)&sBl[(wc * 32 + i * 16 + l16) * 32 + quad * 8];
    }
#pragma unroll
    for (int i = 0; i < 2; i++)
#pragma unroll
      for (int j = 0; j < 2; j++) {
        acc[i][j] = MFMA_BF16(fAh[i], fBh[j], acc[i][j], 0, 0, 0);
        acc[i][j] = MFMA_BF16(fAh[i], fBl[j], acc[i][j], 0, 0, 0);
        acc[i][j] = MFMA_BF16(fAl[i], fBh[j], acc[i][j], 0, 0, 0);
      }
  }
#pragma unroll
  for (int i = 0; i < 2; i++)
#pragma unroll
    for (int j = 0; j < 2; j++)
#pragma unroll
      for (int r = 0; r < 4; r++) {
        int row = wr * 32 + i * 16 + quad * 4 + r;
        int col = wc * 32 + j * 16 + l16;
        C[(size_t)(m0 + row) * Ndim + n0 + col] = acc[i][j][r];
      }
}

// ---------------------------------------------------------------- GRU step (v13: r7 K-loop + vectorized prologue/epilogue)
// K-loop identical to r7's measured family optimum (A direct vmcnt-pipelined,
// B DMA at BK=64). New: prologue/epilogue re-indexed so each thread owns 4
// CONSECUTIVE elements (row = tid>>3, el = (tid&7)*4) -> eg gathers become
// 3x float4, H read 2x bf16x4 (tiled 4-runs contiguous for el%8 in {0,4}),
// sC reads 6x float4, stores 2x bf16x4. Per-element math/inputs/destinations
// bit-identical to v11 (only thread assignment changed) -> absmax unchanged.
__global__ __launch_bounds__(512) void gru_step13(
    const bf16_t* __restrict__ Hh, const bf16_t* __restrict__ Hl,
    const bf16_t* __restrict__ Wph, const bf16_t* __restrict__ Wpl,
    const int* __restrict__ tok, const float* __restrict__ eg,
    const float* __restrict__ b_ih, const float* __restrict__ b_hh,
    bf16_t* __restrict__ Oh, bf16_t* __restrict__ Ol, int t, int final_) {
  __shared__ bf16_t sB[2][2][24 * 512];   // [dbuf][group][hi:0-11|lo:12-23] 96KB
  __shared__ float sC[2][64 * 100];
  __shared__ float sbih[96], sbhh[96];
  const int tid = threadIdx.x;
  const int g = tid >> 8;                       // k-group (k in [g*256,(g+1)*256))
  const int gtid = tid & 255;
  const int ct = blockIdx.y, m0 = blockIdx.x * 64;  // bt fast, ct slow
  const int n0e = ct * 32;
  const int wg = gtid >> 6, lane = tid & 63;
  const int wr = wg >> 1, wc = wg & 1;
  const int quad = lane >> 4, l16 = lane & 15;

  // staging: 24 chunks/group/iter (12 hi + 12 lo), 6 per wave.
#define STAGE_B(buf, it)                                                      \
  {                                                                           \
    _Pragma("unroll") for (int r = 0; r < 6; r++) {                           \
      int c = wg * 6 + r;                                                     \
      int f = (c >= 12) ? (c - 12) : c;                                       \
      int j = f >> 1, ks = f & 1;                                             \
      const bf16_t* srcp = (c < 12) ? Wph : Wpl;                              \
      stage16b(&sB[buf][g][c * 512],                                          \
               &srcp[(size_t)(ct * 6 + j) * 8192 +                            \
                     (size_t)(g * 8 + (it) * 2 + ks) * 512 + lane * 8]);      \
    }                                                                         \
  }

  STAGE_B(0, 0);

  if (tid < 96) {
    sbih[tid] = b_ih[(tid >> 5) * 512 + n0e + (tid & 31)];
    sbhh[tid] = b_hh[(tid >> 5) * 512 + n0e + (tid & 31)];
  }

  // vectorized prologue: thread owns 4 consecutive elements of one row
  const int prow = tid >> 3, pq4 = tid & 7;
  const int pel = pq4 * 4;
  const int pbb = m0 + prow, peG = n0e + pel;
  float pir4[4], piz4[4], pin4[4], phv4[4];
  {
    int tk = tok[pbb * T_ + t];
    float4 a  = *(const float4*)&eg[(size_t)tk * G3_ + peG];
    float4 bz = *(const float4*)&eg[(size_t)tk * G3_ + 512 + peG];
    float4 cn = *(const float4*)&eg[(size_t)tk * G3_ + 1024 + peG];
    pir4[0] = a.x;  pir4[1] = a.y;  pir4[2] = a.z;  pir4[3] = a.w;
    piz4[0] = bz.x; piz4[1] = bz.y; piz4[2] = bz.z; piz4[3] = bz.w;
    pin4[0] = cn.x; pin4[1] = cn.y; pin4[2] = cn.z; pin4[3] = cn.w;
    size_t ptoff = tiled_off(pbb, peG);
    bf16x4 hh4 = *(const bf16x4*)&Hh[ptoff];
    bf16x4 hl4 = *(const bf16x4*)&Hl[ptoff];
#pragma unroll
    for (int j = 0; j < 4; j++) phv4[j] = (float)hh4[j] + (float)hl4[j];
  }

  // A fragment bases (elements): frag (rt, kb) at rt*8192 + kb*512 + lane*8
  const size_t aB0 = (size_t)((m0 >> 4) + wr * 2 + 0) * 8192 + (size_t)g * 4096 + lane * 8;
  const size_t aB1 = (size_t)((m0 >> 4) + wr * 2 + 1) * 8192 + (size_t)g * 4096 + lane * 8;

  f32x4 acc[2][3] = {};
  __syncthreads();  // drain STAGE_B(0,0)
#pragma unroll
  for (int it = 0; it < 4; ++it) {
    const int buf = it & 1;
    if (it < 3) STAGE_B(buf ^ 1, it + 1);
    const bf16_t* sBg = &sB[buf][g][0];
#pragma unroll
    for (int ks2 = 0; ks2 < 2; ++ks2) {
      const int kb = it * 2 + ks2;      // within-group kb 0..7 ascending
      const int ko = kb * 512;
      bf16x8 fah[2], fal[2], fbh[3], fbl[3];
      fah[0] = *(const bf16x8*)&Hh[aB0 + ko];
      fah[1] = *(const bf16x8*)&Hh[aB1 + ko];
      fal[0] = *(const bf16x8*)&Hl[aB0 + ko];
      fal[1] = *(const bf16x8*)&Hl[aB1 + ko];
#pragma unroll
      for (int j = 0; j < 3; j++) {
        int f = (wc * 3 + j) * 2 + ks2;
        fbh[j] = *(const bf16x8*)&sBg[f * 512 + lane * 8];
        fbl[j] = *(const bf16x8*)&sBg[(f + 12) * 512 + lane * 8];
      }
#pragma unroll
      for (int i = 0; i < 2; i++)
#pragma unroll
        for (int j = 0; j < 3; j++) {
          acc[i][j] = MFMA_BF16(fah[i], fbh[j], acc[i][j], 0, 0, 0);
          acc[i][j] = MFMA_BF16(fah[i], fbl[j], acc[i][j], 0, 0, 0);
          acc[i][j] = MFMA_BF16(fal[i], fbh[j], acc[i][j], 0, 0, 0);
        }
    }
    __syncthreads();  // drains next-iter DMA; protects buf reuse
  }
#undef STAGE_B
#pragma unroll
  for (int i = 0; i < 2; i++)
#pragma unroll
    for (int j = 0; j < 3; j++)
#pragma unroll
      for (int r = 0; r < 4; r++)
        sC[g][(wr * 32 + i * 16 + quad * 4 + r) * 100 + wc * 48 + j * 16 + l16] =
            acc[i][j][r];
  __syncthreads();
  // vectorized epilogue (same per-element math as v11)
  {
    float4 hr0 = *(float4*)&sC[0][prow * 100 + pel];
    float4 hr1 = *(float4*)&sC[1][prow * 100 + pel];
    float4 hz0 = *(float4*)&sC[0][prow * 100 + 32 + pel];
    float4 hz1 = *(float4*)&sC[1][prow * 100 + 32 + pel];
    float4 hn0 = *(float4*)&sC[0][prow * 100 + 64 + pel];
    float4 hn1 = *(float4*)&sC[1][prow * 100 + 64 + pel];
    float hrv[4] = {hr0.x + hr1.x, hr0.y + hr1.y, hr0.z + hr1.z, hr0.w + hr1.w};
    float hzv[4] = {hz0.x + hz1.x, hz0.y + hz1.y, hz0.z + hz1.z, hz0.w + hz1.w};
    float hnv[4] = {hn0.x + hn1.x, hn0.y + hn1.y, hn0.z + hn1.z, hn0.w + hn1.w};
    bf16x4 oh4, ol4;
#pragma unroll
    for (int j = 0; j < 4; j++) {
      int el = pel + j;
      float ir = pir4[j] + sbih[el];
      float iz = piz4[j] + sbih[32 + el];
      float in_ = pin4[j] + sbih[64 + el];
      float hr = hrv[j] + sbhh[el];
      float hz = hzv[j] + sbhh[32 + el];
      float hn = hnv[j] + sbhh[64 + el];
      float r = 1.0f / (1.0f + __expf(-(ir + hr)));
      float z = 1.0f / (1.0f + __expf(-(iz + hz)));
      float targ = fminf(fmaxf(in_ + r * hn, -15.0f), 15.0f);
      float e2 = __expf(2.0f * targ);
      float n = (e2 - 1.0f) / (e2 + 1.0f);
      float hnew = (1.0f - z) * n + z * phv4[j];
      bf16_t hh = (bf16_t)hnew;
      oh4[j] = hh;
      ol4[j] = (bf16_t)(hnew - (float)hh);
    }
    if (final_) {
      size_t hidx = (size_t)pbb * 512 + peG;  // row-major for zc GEMM
      *(bf16x4*)&Oh[hidx] = oh4;
      *(bf16x4*)&Ol[hidx] = ol4;
    } else {
      size_t toff = tiled_off(pbb, peG);
      *(bf16x4*)&Oh[toff] = oh4;
      *(bf16x4*)&Ol[toff] = ol4;
    }
  }
}

// ---------------------------------------------------------------- MZI core (qc7: direct-global U reads, no staging)
// r10 measured 47us (vs 58-64 staged): the staged-DMA drain barrier was the
// pacer. r11 lesson: U dedup (2 b's/wave) trades wave count 1:1 — 512 waves
// = 0.5/SIMD collapsed to 173us. qc7's point (2048 waves, 2x dup) is the
// measured optimum of the parallelism-vs-duplication curve.
__device__ inline void apply_u(float4 A, float4 Bv, float& x0r, float& x0i,
                               float& x1r, float& x1i) {
  float n0r = A.x * x0r - A.y * x0i + A.z * x1r - A.w * x1i;
  float n0i = A.x * x0i + A.y * x0r + A.z * x1i + A.w * x1r;
  float n1r = Bv.x * x0r - Bv.y * x0i + Bv.z * x1r - Bv.w * x1i;
  float n1i = Bv.x * x0i + Bv.y * x0r + Bv.z * x1i + Bv.w * x1r;
  x0r = n0r; x0i = n0i; x1r = n1r; x1i = n1i;
}

__global__ __launch_bounds__(256) void qc7(
    const float* __restrict__ zc, const float* __restrict__ bc,
    const float* __restrict__ Uep, const float* __restrict__ Uop,
    bf16_t* __restrict__ prh, bf16_t* __restrict__ prl,
    bf16_t* __restrict__ pih, bf16_t* __restrict__ pil) {
  __shared__ float sred[4];
  __shared__ float4 sEx[2][2][2];  // [layer parity][b-in-block][0:h0.l63 | 1:h1.l0]
  const int tid = threadIdx.x;
  const int wave = tid >> 6, lane = tid & 63;
  const int wb = wave >> 1, h = wave & 1;
  const int b = blockIdx.x * 2 + wb;
  const int e0 = h * 512 + lane * 8;

  float xr[8], xi[8];
  {
    const float4* zr4 = (const float4*)&zc[(size_t)b * M2_ + e0];
    const float4* zi4 = (const float4*)&zc[(size_t)b * M2_ + M_ + e0];
    const float4* br4 = (const float4*)&bc[e0];
    const float4* bi4 = (const float4*)&bc[M_ + e0];
#pragma unroll
    for (int q = 0; q < 2; q++) {
      float4 a = zr4[q], bb = br4[q];
      xr[4 * q + 0] = a.x + bb.x; xr[4 * q + 1] = a.y + bb.y;
      xr[4 * q + 2] = a.z + bb.z; xr[4 * q + 3] = a.w + bb.w;
      float4 c2 = zi4[q], d = bi4[q];
      xi[4 * q + 0] = c2.x + d.x; xi[4 * q + 1] = c2.y + d.y;
      xi[4 * q + 2] = c2.z + d.z; xi[4 * q + 3] = c2.w + d.w;
    }
  }
  {
    float s = 0.0f;
#pragma unroll
    for (int k = 0; k < 8; k++) s += xr[k] * xr[k] + xi[k] * xi[k];
    for (int off = 32; off; off >>= 1) s += __shfl_xor(s, off);
    if (lane == 0) sred[wave] = s;
    __syncthreads();
    float inv = 1.0f / sqrtf(sred[2 * wb] + sred[2 * wb + 1] + 1e-8f);
#pragma unroll
    for (int k = 0; k < 8; k++) { xr[k] *= inv; xi[k] *= inv; }
  }
  if (h == 0 && lane == 63) sEx[0][wb][0] = make_float4(xr[6], xi[6], xr[7], xi[7]);
  if (h == 1 && lane == 0)  sEx[0][wb][1] = make_float4(xr[0], xi[0], xr[1], xi[1]);
  __syncthreads();

#pragma unroll 1
  for (int l = 0; l < L_; ++l) {
    const int buf = l & 1;
    const float* Ub = &Uep[(size_t)l * 4096];
    const float* Ob = &Uop[(size_t)l * 4096];
    // issue ALL U loads first (16 x 1KB contiguous wave-loads in flight)
    float4 eA[4], eB[4], oA[3], oB[3], A3, B3;
#pragma unroll
    for (int j = 0; j < 4; j++) {
      eA[j] = *(const float4*)&Ub[(j * 4 + h) * 256 + lane * 4];
      eB[j] = *(const float4*)&Ub[(j * 4 + 2 + h) * 256 + lane * 4];
    }
#pragma unroll
    for (int j = 0; j < 3; j++) {
      oA[j] = *(const float4*)&Ob[(j * 4 + h) * 256 + lane * 4];
      oB[j] = *(const float4*)&Ob[(j * 4 + 2 + h) * 256 + lane * 4];
    }
    A3 = *(const float4*)&Ob[(12 + h) * 256 + lane * 4];
    B3 = *(const float4*)&Ob[(14 + h) * 256 + lane * 4];
    // partner pre-layer boundary values (written end of previous layer)
    float4 par = make_float4(0.f, 0.f, 0.f, 0.f);
    if (h == 0 && lane == 63) par = sEx[buf][wb][1];  // h1.l0's (x0,x1)
    if (h == 1 && lane == 0)  par = sEx[buf][wb][0];  // h0.l63's (x6,x7)
    // even pass: 4 lane-local pairs
#pragma unroll
    for (int j = 0; j < 4; j++)
      apply_u(eA[j], eB[j], xr[2 * j], xi[2 * j], xr[2 * j + 1], xi[2 * j + 1]);
    // redundantly recompute partner's post-even boundary value
    float exr = 0.f, exi = 0.f;
    if (h == 0 && lane == 63) {
      float4 Ae = *(const float4*)&Ub[1 * 256];  // even p=256 A-row (j=0,h=1)
      exr = Ae.x * par.x - Ae.y * par.y + Ae.z * par.z - Ae.w * par.w;
      exi = Ae.x * par.y + Ae.y * par.x + Ae.z * par.w + Ae.w * par.z;
    }
    if (h == 1 && lane == 0) {
      float4 Be = *(const float4*)&Ub[14 * 256 + 252];  // even p=255 B-row (j=3,h=0)
      exr = Be.x * par.x - Be.y * par.y + Be.z * par.z - Be.w * par.w;
      exi = Be.x * par.y + Be.y * par.x + Be.z * par.w + Be.w * par.z;
    }
    // odd pass: 3 interior lane-local pairs
#pragma unroll
    for (int j = 0; j < 3; j++)
      apply_u(oA[j], oB[j], xr[2 * j + 1], xi[2 * j + 1], xr[2 * j + 2],
              xi[2 * j + 2]);
    // boundary pair j=3: (x[7], next element)
    float nr = __shfl_down(xr[0], 1), ni = __shfl_down(xi[0], 1);
    if (h == 0 && lane == 63) { nr = exr; ni = exi; }  // cross-wave v1
    float srr = 0.f, sii = 0.f;
    if (!(h == 1 && lane == 63)) {  // (1023,1024) doesn't exist
      float n0r = A3.x * xr[7] - A3.y * xi[7] + A3.z * nr - A3.w * ni;
      float n0i = A3.x * xi[7] + A3.y * xr[7] + A3.z * ni + A3.w * nr;
      srr = B3.x * xr[7] - B3.y * xi[7] + B3.z * nr - B3.w * ni;
      sii = B3.x * xi[7] + B3.y * xr[7] + B3.z * ni + B3.w * nr;
      xr[7] = n0r; xi[7] = n0i;
    }
    float nx0r = 0.f, nx0i = 0.f;
    if (h == 1 && lane == 0) {  // cross pair q=255: v0=partner(ex), v1=own x[0]
      float4 Bc = *(const float4*)&Ob[14 * 256 + 252];  // odd q=255 B-row
      nx0r = Bc.x * exr - Bc.y * exi + Bc.z * xr[0] - Bc.w * xi[0];
      nx0i = Bc.x * exi + Bc.y * exr + Bc.z * xi[0] + Bc.w * xr[0];
    }
    float rr = __shfl_up(srr, 1), ri2 = __shfl_up(sii, 1);
    if (lane > 0) { xr[0] = rr; xi[0] = ri2; }
    if (h == 1 && lane == 0) { xr[0] = nx0r; xi[0] = nx0i; }
    // publish boundary values for next layer (parity-buffered: no race)
    if (h == 0 && lane == 63)
      sEx[1 - buf][wb][0] = make_float4(xr[6], xi[6], xr[7], xi[7]);
    if (h == 1 && lane == 0)
      sEx[1 - buf][wb][1] = make_float4(xr[0], xi[0], xr[1], xi[1]);
    __syncthreads();  // sEx exchange visibility only (no DMA drain)
  }
  size_t base = (size_t)b * M_ + e0;
  bf16x8 vh, vl, wh, wl;
#pragma unroll
  for (int k = 0; k < 8; k++) {
    float vr = xr[k], vi = xi[k];
    bf16_t h1 = (bf16_t)vr;
    vh[k] = h1; vl[k] = (bf16_t)(vr - (float)h1);
    bf16_t h2 = (bf16_t)vi;
    wh[k] = h2; wl[k] = (bf16_t)(vi - (float)h2);
  }
  *(bf16x8*)&prh[base] = vh;
  *(bf16x8*)&prl[base] = vl;
  *(bf16x8*)&pih[base] = wh;
  *(bf16x8*)&pil[base] = wl;
}

// ---------------------------------------------------------------- readout (r7 known-good)
// r9 lesson: K-split pays only when MFMA-per-interval is thin; readout has
// 48 MFMA/interval (compute-covered at 1 wave/SIMD).
__global__ __launch_bounds__(256) void readout_mfma(
    const bf16_t* __restrict__ Arh, const bf16_t* __restrict__ Arl,
    const bf16_t* __restrict__ Aih, const bf16_t* __restrict__ Ail,
    const bf16_t* __restrict__ Brh, const bf16_t* __restrict__ Brl,
    const bf16_t* __restrict__ Bih, const bf16_t* __restrict__ Bil,
    float* __restrict__ out) {
  __shared__ bf16_t sArh[64 * 32], sArl[64 * 32], sAih[64 * 32], sAil[64 * 32];
  __shared__ bf16_t sBrh[64 * 32], sBrl[64 * 32], sBih[64 * 32], sBil[64 * 32];
  const int tid = threadIdx.x;
  const int b0 = blockIdx.y * 64, v0 = blockIdx.x * 64;
  const int wave = tid >> 6, lane = tid & 63;
  const int wr = wave >> 1, wc = wave & 1;
  const int quad = lane >> 4, l16 = lane & 15;
  f32x4 aP[2][2] = {}, aQ[2][2] = {}, aI[2][2] = {};
  const int srow = tid >> 2, sk = (tid & 3) * 8;

  for (int k0 = 0; k0 < M_; k0 += 32) {
    size_t aoff = (size_t)(b0 + srow) * M_ + k0 + sk;
    size_t boff = (size_t)(v0 + srow) * M_ + k0 + sk;
    bf16x8 v0r = *(const bf16x8*)&Arh[aoff];
    bf16x8 v1r = *(const bf16x8*)&Arl[aoff];
    bf16x8 v2r = *(const bf16x8*)&Aih[aoff];
    bf16x8 v3r = *(const bf16x8*)&Ail[aoff];
    bf16x8 v4r = *(const bf16x8*)&Brh[boff];
    bf16x8 v5r = *(const bf16x8*)&Brl[boff];
    bf16x8 v6r = *(const bf16x8*)&Bih[boff];
    bf16x8 v7r = *(const bf16x8*)&Bil[boff];
    __syncthreads();
    *(bf16x8*)&sArh[srow * 32 + sk] = v0r;
    *(bf16x8*)&sArl[srow * 32 + sk] = v1r;
    *(bf16x8*)&sAih[srow * 32 + sk] = v2r;
    *(bf16x8*)&sAil[srow * 32 + sk] = v3r;
    *(bf16x8*)&sBrh[srow * 32 + sk] = v4r;
    *(bf16x8*)&sBrl[srow * 32 + sk] = v5r;
    *(bf16x8*)&sBih[srow * 32 + sk] = v6r;
    *(bf16x8*)&sBil[srow * 32 + sk] = v7r;
    __syncthreads();
    bf16x8 fArh[2], fArl[2], fAih[2], fAil[2], fBrh[2], fBrl[2], fBih[2], fBil[2];
#pragma unroll
    for (int i = 0; i < 2; i++) {
      int ra = (wr * 32 + i * 16 + l16) * 32 + quad * 8;
      int rb = (wc * 32 + i * 16 + l16) * 32 + quad * 8;
      fArh[i] = *(const bf16x8*)&sArh[ra];
      fArl[i] = *(const bf16x8*)&sArl[ra];
      fAih[i] = *(const bf16x8*)&sAih[ra];
      fAil[i] = *(const bf16x8*)&sAil[ra];
      fBrh[i] = *(const bf16x8*)&sBrh[rb];
      fBrl[i] = *(const bf16x8*)&sBrl[rb];
      fBih[i] = *(const bf16x8*)&sBih[rb];
      fBil[i] = *(const bf16x8*)&sBil[rb];
    }
#pragma unroll
    for (int i = 0; i < 2; i++)
#pragma unroll
      for (int j = 0; j < 2; j++) {
        aP[i][j] = MFMA_BF16(fArh[i], fBrh[j], aP[i][j], 0, 0, 0);
        aP[i][j] = MFMA_BF16(fArh[i], fBrl[j], aP[i][j], 0, 0, 0);
        aP[i][j] = MFMA_BF16(fArl[i], fBrh[j], aP[i][j], 0, 0, 0);
        aQ[i][j] = MFMA_BF16(fAih[i], fBih[j], aQ[i][j], 0, 0, 0);
        aQ[i][j] = MFMA_BF16(fAih[i], fBil[j], aQ[i][j], 0, 0, 0);
        aQ[i][j] = MFMA_BF16(fAil[i], fBih[j], aQ[i][j], 0, 0, 0);
        aI[i][j] = MFMA_BF16(fArh[i], fBih[j], aI[i][j], 0, 0, 0);
        aI[i][j] = MFMA_BF16(fArh[i], fBil[j], aI[i][j], 0, 0, 0);
        aI[i][j] = MFMA_BF16(fArl[i], fBih[j], aI[i][j], 0, 0, 0);
        aI[i][j] = MFMA_BF16(fAih[i], fBrh[j], aI[i][j], 0, 0, 0);
        aI[i][j] = MFMA_BF16(fAih[i], fBrl[j], aI[i][j], 0, 0, 0);
        aI[i][j] = MFMA_BF16(fAil[i], fBrh[j], aI[i][j], 0, 0, 0);
      }
  }
#pragma unroll
  for (int i = 0; i < 2; i++)
#pragma unroll
    for (int j = 0; j < 2; j++)
#pragma unroll
      for (int r = 0; r < 4; r++) {
        int row = wr * 32 + i * 16 + quad * 4 + r;
        int col = wc * 32 + j * 16 + l16;
        float re = aP[i][j][r] - aQ[i][j][r];
        float im = aI[i][j][r];
        out[(size_t)(b0 + row) * V_ + v0 + col] = logf(re * re + im * im + 1e-12f);
      }
}

// ---------------------------------------------------------------- logsumexp
__global__ __launch_bounds__(256) void lse_kernel(float* __restrict__ out) {
  __shared__ float redm[4], reds[4];
  const int b = blockIdx.x, t = threadIdx.x;
  float4 v = *(float4*)&out[(size_t)b * V_ + 4 * t];
  float mx = fmaxf(fmaxf(v.x, v.y), fmaxf(v.z, v.w));
  for (int off = 32; off; off >>= 1) mx = fmaxf(mx, __shfl_down(mx, off, 64));
  if ((t & 63) == 0) redm[t >> 6] = mx;
  __syncthreads();
  mx = fmaxf(fmaxf(redm[0], redm[1]), fmaxf(redm[2], redm[3]));
  float s = expf(v.x - mx) + expf(v.y - mx) + expf(v.z - mx) + expf(v.w - mx);
  for (int off = 32; off; off >>= 1) s += __shfl_down(s, off, 64);
  if ((t & 63) == 0) reds[t >> 6] = s;
  __syncthreads();
  s = reds[0] + reds[1] + reds[2] + reds[3];
  float lse = mx + logf(s);
  v.x -= lse; v.y -= lse; v.z -= lse; v.w -= lse;
  *(float4*)&out[(size_t)b * V_ + 4 * t] = v;
}

// ---------------------------------------------------------------- launch
extern "C" void kernel_launch(void* const* d_in, const int* in_sizes, int n_in,
                              void* d_out, int out_size, void* d_ws, size_t ws_size,
                              hipStream_t stream) {
  const int*   tokens = (const int*)d_in[0];
  const float* embed  = (const float*)d_in[1];
  const float* W_ih   = (const float*)d_in[2];
  const float* W_hh   = (const float*)d_in[3];
  const float* b_ih   = (const float*)d_in[4];
  const float* b_hh   = (const float*)d_in[5];
  const float* Wc     = (const float*)d_in[6];
  const float* bc     = (const float*)d_in[7];
  const float* phase  = (const float*)d_in[8];
  const float* theta_e = (const float*)d_in[9];
  const float* phi_e  = (const float*)d_in[10];
  const float* rho_e  = (const float*)d_in[11];
  const float* theta_o = (const float*)d_in[12];
  const float* phi_o  = (const float*)d_in[13];
  const float* rho_o  = (const float*)d_in[14];
  const float* R_real = (const float*)d_in[15];
  const float* R_imag = (const float*)d_in[16];
  float* out = (float*)d_out;

  char* w = (char*)d_ws;
  auto alloc = [&](size_t bytes) -> void* {
    void* p = (void*)w;
    w += (bytes + 255) & ~(size_t)255;
    return p;
  };
  // region0: weight splits; later aliased by psi hi/lo (dead by then)
  char* region0 = w;
  bf16_t* emb_hi = (bf16_t*)alloc((size_t)V_ * E_ * 2);
  bf16_t* emb_lo = (bf16_t*)alloc((size_t)V_ * E_ * 2);
  bf16_t* wih_hi = (bf16_t*)alloc((size_t)G3_ * E_ * 2);
  bf16_t* wih_lo = (bf16_t*)alloc((size_t)G3_ * E_ * 2);
  bf16_t* wc_hi  = (bf16_t*)alloc((size_t)M2_ * E_ * 2);
  bf16_t* wc_lo  = (bf16_t*)alloc((size_t)M2_ * E_ * 2);
  // region1: eg + Wp; later aliased by zc
  char* region1 = w;
  float*  eg     = (float*)alloc((size_t)V_ * G3_ * 4);
  bf16_t* Wp_hi  = (bf16_t*)alloc((size_t)G3_ * E_ * 2);
  bf16_t* Wp_lo  = (bf16_t*)alloc((size_t)G3_ * E_ * 2);
  // persistent
  bf16_t* h0_hi = (bf16_t*)alloc((size_t)B_ * E_ * 2);
  bf16_t* h0_lo = (bf16_t*)alloc((size_t)B_ * E_ * 2);
  bf16_t* h1_hi = (bf16_t*)alloc((size_t)B_ * E_ * 2);
  bf16_t* h1_lo = (bf16_t*)alloc((size_t)B_ * E_ * 2);
  bf16_t* rr_hi = (bf16_t*)alloc((size_t)V_ * M_ * 2);
  bf16_t* rr_lo = (bf16_t*)alloc((size_t)V_ * M_ * 2);
  bf16_t* ri_hi = (bf16_t*)alloc((size_t)V_ * M_ * 2);
  bf16_t* ri_lo = (bf16_t*)alloc((size_t)V_ * M_ * 2);
  float*  Uep   = (float*)alloc((size_t)L_ * 4096 * 4);
  float*  Uop   = (float*)alloc((size_t)L_ * 4096 * 4);

  // aliases
  float*  zc  = (float*)region1;
  bf16_t* prh = (bf16_t*)(region0 + 0 * 2097152);
  bf16_t* prl = (bf16_t*)(region0 + 1 * 2097152);
  bf16_t* pih = (bf16_t*)(region0 + 2 * 2097152);
  bf16_t* pil = (bf16_t*)(region0 + 3 * 2097152);

  hipMemsetAsync(h0_hi, 0, (size_t)B_ * E_ * 2 * 2, stream);

  // ONE fused prep launch
  prep_all<<<6016, 256, 0, stream>>>(
      embed, emb_hi, emb_lo, W_ih, wih_hi, wih_lo, Wc, wc_hi, wc_lo, R_real,
      rr_hi, rr_lo, R_imag, ri_hi, ri_lo, W_hh, Wp_hi, Wp_lo, phase, theta_e,
      phi_e, rho_e, Uep, theta_o, phi_o, rho_o, Uop);

  // eg = embed @ W_ih^T  (V x 3E)
  {
    dim3 grid(G3_ / 64, V_ / 64);
    gemm_bt_mfma_split<<<grid, 256, 0, stream>>>(emb_hi, emb_lo, wih_hi, wih_lo,
                                                 eg, G3_, E_);
  }

  // GRU: 64 per-step launches; r7 K-loop + vectorized prologue/epilogue
  for (int t = 0; t < T_; ++t) {
    const bf16_t* ih = (t & 1) ? h1_hi : h0_hi;
    const bf16_t* il = (t & 1) ? h1_lo : h0_lo;
    bf16_t* oh = (t & 1) ? h0_hi : h1_hi;
    bf16_t* ol = (t & 1) ? h0_lo : h1_lo;
    dim3 grid(16, 16);  // bt fast, ct slow (L2 locality)
    gru_step13<<<grid, 512, 0, stream>>>(ih, il, Wp_hi, Wp_lo, tokens, eg,
                                         b_ih, b_hh, oh, ol, t,
                                         (t == T_ - 1) ? 1 : 0);
  }

  // zc = h @ Wc^T  (B x 2M); final h (row-major) in buffer 0 after t=63
  {
    dim3 grid(M2_ / 64, B_ / 64);
    gemm_bt_mfma_split<<<grid, 256, 0, stream>>>(h0_hi, h0_lo, wc_hi, wc_lo,
                                                 zc, M2_, E_);
  }

  // MZI stack (qc7: direct-global U reads, no staging)
  qc7<<<B_ / 2, 256, 0, stream>>>(zc, bc, Uep, Uop, prh, prl, pih, pil);

  // readout (r7 known-good)
  {
    dim3 grid(V_ / 64, B_ / 64);
    readout_mfma<<<grid, 256, 0, stream>>>(prh, prl, pih, pil, rr_hi, rr_lo,
                                           ri_hi, ri_lo, out);
  }

  // logsumexp
  lse_kernel<<<B_, 256, 0, stream>>>(out);
}